// Round 11
// baseline (711.718 us; speedup 1.0000x reference)
//
#include <hip/hip_runtime.h>
#include <math.h>

constexpr int Hc = 80, Wc = 80, Bn = 4, C1 = 256, C2 = 256;
constexpr int HWn = Hc * Wc;          // 6400
constexpr int NPIX = Bn * HWn;        // 25600
constexpr int OFFC = 27;
constexpr int KK   = 2304;            // C1*9

typedef short bf16x8 __attribute__((ext_vector_type(8)));
typedef float f32x4  __attribute__((ext_vector_type(4)));

__device__ __forceinline__ unsigned f2bf(float f) {   // RNE to bf16 bits
    unsigned u = __float_as_uint(f);
    return (u + 0x7FFF + ((u >> 16) & 1)) >> 16;
}

// pack 2 floats -> hi-word (2 bf16) + lo-residual-word (2 bf16) via cvt_pk
__device__ __forceinline__ void pack2(float v0, float v1, unsigned& hw, unsigned& lw) {
    unsigned h;
    asm("v_cvt_pk_bf16_f32 %0, %1, %2" : "=v"(h) : "v"(v0), "v"(v1));
    float r0 = v0 - __uint_as_float(h << 16);
    float r1 = v1 - __uint_as_float(h & 0xffff0000u);
    unsigned l;
    asm("v_cvt_pk_bf16_f32 %0, %1, %2" : "=v"(l) : "v"(r0), "v"(r1));
    hw = h; lw = l;
}

// ---------------- kernel 0a: weight prep -> per-step B images (hi bf16 only) ----
// wB1[s][oc][40] bf16, s = p*8+cc (72 steps); kc<32 real, else pad 0
__global__ __launch_bounds__(256) void k_wprep(const float* __restrict__ weight,
                                               unsigned short* __restrict__ wB1)
{
    int e = blockIdx.x * 256 + threadIdx.x;   // 0 .. 737279
    int kc = e % 40;
    int oc = (e / 40) & 255;
    int s  = e / 10240;
    int p  = s >> 3, cc = s & 7;
    float w = 0.f;
    if (kc < 32) w = weight[((size_t)oc * C1 + cc * 32 + kc) * 9 + p];
    wB1[e] = (unsigned short)f2bf(w);
}

// ---------------- kernel 0b: offset-conv weight transpose -> wOT[c][244] -------
__global__ __launch_bounds__(256) void k_woprep(const float* __restrict__ w_off,
                                                float* __restrict__ wOT)
{
    int e = blockIdx.x * 256 + threadIdx.x;   // 0 .. 62463 (244 blocks)
    int c = e / 244, r = e - c * 244;
    float v = 0.f;
    if (r < 243) {
        int ch = r / 9, p = r - ch * 9;
        v = w_off[((size_t)ch * C1 + c) * 9 + p];
    }
    wOT[e] = v;
}

// ---------------- kernel 1a: init off buffer with b_off ----------------
__global__ __launch_bounds__(256) void k_offinit(const float* __restrict__ b_off,
                                                 float* __restrict__ off)
{
    int t = blockIdx.x * 256 + threadIdx.x;   // 0 .. 691199
    int ch = (t / HWn) % OFFC;
    off[t] = b_off[ch];
}

// ---------------- kernel 1b: offset conv v3 (LDS x-tile, unrolled reg weights) --
__global__ __launch_bounds__(256) void k_offconv2(const float* __restrict__ x,
                                                  const float* __restrict__ wOT,
                                                  float* __restrict__ off)
{
    __shared__ float xs[8][18][18];

    int tid  = threadIdx.x;
    int bidx = blockIdx.x;                 // 0..799
    int wt = bidx % 5;
    int ht = (bidx / 5) % 5;
    int b  = (bidx / 25) % 4;
    int cg = bidx / 100;                   // 0..7
    int h0 = ht * 16, w0 = wt * 16;
    int c0 = cg * 32;
    int ph = tid >> 4, pw = tid & 15;

    float acc[27];
    #pragma unroll
    for (int ch = 0; ch < 27; ++ch) acc[ch] = 0.f;

    const float* xb = x + (size_t)b * C1 * HWn;

    for (int cc = 0; cc < 4; ++cc) {       // 4 chunks of 8 channels
        __syncthreads();
        for (int idx = tid; idx < 8 * 324; idx += 256) {
            int cl  = idx / 324;
            int rem = idx - cl * 324;
            int r   = rem / 18;
            int col = rem - r * 18;
            int gh = h0 - 1 + r, gw = w0 - 1 + col;
            float v = 0.f;
            if (gh >= 0 && gh < Hc && gw >= 0 && gw < Wc)
                v = xb[(size_t)(c0 + cc * 8 + cl) * HWn + gh * Wc + gw];
            xs[cl][r][col] = v;
        }
        __syncthreads();
        #pragma unroll
        for (int cl = 0; cl < 8; ++cl) {
            float xr[9];
            #pragma unroll
            for (int kh = 0; kh < 3; ++kh)
                #pragma unroll
                for (int kw = 0; kw < 3; ++kw)
                    xr[kh * 3 + kw] = xs[cl][ph + kh][pw + kw];
            int c = c0 + cc * 8 + cl;
            const float4* wv4 = (const float4*)&wOT[c * 244];
            #pragma unroll
            for (int j = 0; j < 61; ++j) {
                float4 wj = wv4[j];
                #pragma unroll
                for (int u = 0; u < 4; ++u) {
                    constexpr int NW = 243;
                    int idx = 4 * j + u;
                    if (idx < NW)
                        acc[idx / 9] = fmaf(xr[idx % 9], (&wj.x)[u], acc[idx / 9]);
                }
            }
        }
    }

    int hw = (h0 + ph) * Wc + (w0 + pw);
    float* ob = off + (size_t)b * OFFC * HWn + hw;
    #pragma unroll
    for (int ch = 0; ch < 27; ++ch)
        atomicAdd(ob + (size_t)ch * HWn, acc[ch]);
}

// ---------------- kernel 1c: materialize masked bilinear patches ----------------
// Ahi/Alo[NPIX][KK] bf16 planes, k = p*256 + c (p-major, matches wB1 steps).
// Thread = (pixel, tap p, 8-channel group). Barrier-free, TLP hides gather
// latency (round-9 lesson: this latency cannot live inside the GEMM K-loop).
// XCD-chunked: 28800 = 8 x 3600 -> each XCD sees a 3.25MB x-slice (L2-fit).
__global__ __launch_bounds__(256) void k_gather(const float* __restrict__ x,
                                                const float* __restrict__ off,
                                                unsigned short* __restrict__ Ahi,
                                                unsigned short* __restrict__ Alo)
{
    int bid = ((blockIdx.x & 7) * 3600) + (blockIdx.x >> 3);
    int p   = bid % 9;
    int pxg = bid / 9;                  // 0..3199
    int t   = threadIdx.x;
    int cg  = t & 31, pxo = t >> 5;
    int px  = pxg * 8 + pxo;            // global pixel row 0..25599
    int b   = px / HWn, hw = px - b * HWn;
    int h = hw / Wc, w = hw - h * Wc;
    int ii = p / 3, jj = p - ii * 3;

    const float* ob = off + (size_t)b * OFFC * HWn + hw;
    float dy = ob[(2 * p) * HWn];
    float dx = ob[(2 * p + 1) * HWn];
    float mv = ob[(18 + p) * HWn];
    float mask = 1.0f / (1.0f + expf(-mv));
    float ys = dy + (float)(h - 1 + ii);
    float xsv = dx + (float)(w - 1 + jj);
    float y0f = floorf(ys), x0f = floorf(xsv);
    float wy = ys - y0f, wx = xsv - x0f;
    int y0 = (int)y0f, x0 = (int)x0f;
    int y1 = y0 + 1, x1 = x0 + 1;
    float vy0 = (y0 >= 0 && y0 < Hc) ? 1.f : 0.f;
    float vy1 = (y1 >= 0 && y1 < Hc) ? 1.f : 0.f;
    float vx0 = (x0 >= 0 && x0 < Wc) ? 1.f : 0.f;
    float vx1 = (x1 >= 0 && x1 < Wc) ? 1.f : 0.f;
    float4 wv;
    wv.x = mask * (1.f - wy) * (1.f - wx) * vy0 * vx0;
    wv.y = mask * (1.f - wy) * wx         * vy0 * vx1;
    wv.z = mask * wy         * (1.f - wx) * vy1 * vx0;
    wv.w = mask * wy         * wx         * vy1 * vx1;
    int cy0 = min(max(y0, 0), Hc - 1), cy1 = min(max(y1, 0), Hc - 1);
    int cx0 = min(max(x0, 0), Wc - 1), cx1 = min(max(x1, 0), Wc - 1);
    int o00 = cy0 * Wc + cx0, o01 = cy0 * Wc + cx1;
    int o10 = cy1 * Wc + cx0, o11 = cy1 * Wc + cx1;

    const float* xp = x + (size_t)b * C1 * HWn + (size_t)(cg * 8) * HWn;
    float g00[8], g01[8], g10[8], g11[8];
    {
        unsigned co = 0;
        #pragma unroll
        for (int j = 0; j < 8; ++j) {
            g00[j] = xp[co + o00];
            g01[j] = xp[co + o01];
            g10[j] = xp[co + o10];
            g11[j] = xp[co + o11];
            co += HWn;
        }
    }
    float v[8];
    #pragma unroll
    for (int j = 0; j < 8; ++j)
        v[j] = fmaf(wv.x, g00[j], fmaf(wv.y, g01[j],
               fmaf(wv.z, g10[j], wv.w * g11[j])));
    unsigned hu[4], lu[4];
    #pragma unroll
    for (int j = 0; j < 4; ++j) pack2(v[2 * j], v[2 * j + 1], hu[j], lu[j]);

    size_t aidx = (size_t)px * KK + p * 256 + cg * 8;
    *(uint4*)&Ahi[aidx] = make_uint4(hu[0], hu[1], hu[2], hu[3]);
    *(uint4*)&Alo[aidx] = make_uint4(lu[0], lu[1], lu[2], lu[3]);
}

// ------------- kernel 2: dense streaming MFMA GEMM v6 -------------
// A[NPIX][KK] bf16 hi+lo planes (pre-gathered), B = wB1 per-step images.
// BM=32, BN=256, grid 800, XCD-chunked. 4 waves: (mi, nh) = 16px x 128oc.
// A-frags: direct global->VGPR dwordx4, 2-deep prefetch, 3-slot rotation
// (rule #20: static slot naming). B: gll double-buffer. Raw s_barrier +
// counted vmcnt so prefetch survives the barrier (T4).
// vmcnt COUNT DERIVATION (round-10 bug: was 4 -> race): at each step's wait
// the outstanding FIFO is [gllB(s) x5, loadA(s+1) x2]; own gll MUST be
// drained before s_barrier (LDS-visibility protocol), so wait until only
// the 2 newer A-loads remain -> vmcnt(2). Prologue: [loadA(0) x2,
// gllB(0) x5, loadA(1) x2] -> vmcnt(2) drains buf0 exactly. vmcnt(0) only
// at the last step. LDS 40KB -> 4 blocks/CU (16 waves/CU).
__global__ __launch_bounds__(256, 4) void k_dmfma(const unsigned short* __restrict__ Ahi,
                                                  const unsigned short* __restrict__ Alo,
                                                  const unsigned short* __restrict__ wB1,
                                                  const float* __restrict__ bias,
                                                  float* __restrict__ out)
{
    __shared__ __align__(16) char smem[40960];   // B dbuf [2][256][40] u16
    float* Tb = (float*)smem;                    // epilogue alias [32][33] f32

    int t  = threadIdx.x;
    int wv = t >> 6, lane = t & 63;
    int li = lane & 15, kg = lane >> 4;
    int mi = wv & 1;                   // m-tile (16 px)
    int nh = wv >> 1;                  // oc 128-half

    int mtile = ((blockIdx.x & 7) * 100) + (blockIdx.x >> 3);
    int m0  = mtile * 32;
    int b   = m0 / HWn;
    int hw0 = m0 - b * HWn;
    int row = m0 + mi * 16 + li;
    const unsigned short* arow_h = Ahi + (size_t)row * KK + kg * 8;
    const unsigned short* arow_l = Alo + (size_t)row * KK + kg * 8;

    auto gllB = [&](int s, int buf) {
        const char* src = (const char*)wB1 + (size_t)s * 20480 + wv * 5120 + lane * 16;
        char* dst = smem + buf * 20480 + wv * 5120;
        #pragma unroll
        for (int i = 0; i < 5; ++i)
            __builtin_amdgcn_global_load_lds(
                (const __attribute__((address_space(1))) void*)(src + i * 1024),
                (__attribute__((address_space(3))) void*)(dst + i * 1024),
                16, 0, 0);
    };
    auto loadA = [&](int s, uint4& hh, uint4& ll) {
        int col = (s >> 3) * 256 + (s & 7) * 32;
        hh = *(const uint4*)(arow_h + col);
        ll = *(const uint4*)(arow_l + col);
    };

    f32x4 acc[8];
    #pragma unroll
    for (int n = 0; n < 8; ++n) acc[n] = (f32x4){0.f, 0.f, 0.f, 0.f};

    uint4 a0h, a0l, a1h, a1l, a2h, a2l;
    // prologue: A(0), gllB(0)->buf0, A(1)   [oldest-first so vmcnt(2) works at s=0]
    loadA(0, a0h, a0l);
    gllB(0, 0);
    loadA(1, a1h, a1l);

    auto step = [&](int s, uint4& ch, uint4& cl, uint4& lh, uint4& llo) {
        if (s == 71) { asm volatile("s_waitcnt vmcnt(0)" ::: "memory"); }
        else         { asm volatile("s_waitcnt vmcnt(2)" ::: "memory"); }
        __builtin_amdgcn_s_barrier();
        __builtin_amdgcn_sched_barrier(0);
        int cur = s & 1;
        if (s < 71) gllB(s + 1, cur ^ 1);
        __builtin_amdgcn_sched_barrier(0);
        if (s < 70) loadA(s + 2, lh, llo);
        __builtin_amdgcn_sched_barrier(0);
        const unsigned short* Bc = (const unsigned short*)(smem + cur * 20480);
        bf16x8 ah = __builtin_bit_cast(bf16x8, ch);
        bf16x8 al = __builtin_bit_cast(bf16x8, cl);
        __builtin_amdgcn_s_setprio(1);
        #pragma unroll
        for (int nt = 0; nt < 8; ++nt) {
            int oc = nh * 128 + nt * 16 + li;
            bf16x8 bv = *(const bf16x8*)&Bc[oc * 40 + kg * 8];
            acc[nt] = __builtin_amdgcn_mfma_f32_16x16x32_bf16(ah, bv, acc[nt], 0, 0, 0);
            acc[nt] = __builtin_amdgcn_mfma_f32_16x16x32_bf16(al, bv, acc[nt], 0, 0, 0);
        }
        __builtin_amdgcn_s_setprio(0);
    };

    for (int s = 0; s < 72; s += 3) {   // 3-slot rotation: consume / in-flight / load
        step(s,     a0h, a0l, a2h, a2l);
        step(s + 1, a1h, a1l, a0h, a0l);
        step(s + 2, a2h, a2l, a1h, a1l);
    }

    // ---- epilogue: 8 phases of 32 oc through Tb[32][33] ----
    // D frag: pixel = mi*16 + kg*4 + r ; oc = nh*128 + nt*16 + li
    #pragma unroll
    for (int q = 0; q < 8; ++q) {
        __syncthreads();
        if (nh == (q >> 2)) {
            #pragma unroll
            for (int j = 0; j < 2; ++j) {
                int nt = (q & 3) * 2 + j;
                f32x4 a = acc[nt];
                int rrw = j * 16 + li;              // oc row 0..31
                int col = mi * 16 + kg * 4;         // pixel col
                #pragma unroll
                for (int r = 0; r < 4; ++r)
                    Tb[rrw * 33 + col + r] = a[r];
            }
        }
        __syncthreads();
        int px = t & 31;
        int rw = t >> 5;                    // 0..7
        #pragma unroll
        for (int it = 0; it < 4; ++it) {
            int r  = it * 8 + rw;           // 0..31
            int oc = q * 32 + r;
            out[(size_t)(b * C2 + oc) * HWn + hw0 + px] = Tb[r * 33 + px] + bias[oc];
        }
    }
}

// ---------------- kernel 3: BN stats (per-channel mean, invstd) ----------------
__global__ __launch_bounds__(256) void k_bnstats(const float* __restrict__ out,
                                                 float* __restrict__ stats)
{
    int oc = blockIdx.x;
    double s = 0.0, ss = 0.0;
    for (int i = threadIdx.x; i < NPIX; i += 256) {
        int bb = i / HWn;
        int hw = i - bb * HWn;
        float v = out[(size_t)(bb * C2 + oc) * HWn + hw];
        s  += (double)v;
        ss += (double)v * (double)v;
    }
    __shared__ double ls[256], lss[256];
    ls[threadIdx.x] = s; lss[threadIdx.x] = ss;
    __syncthreads();
    for (int st = 128; st > 0; st >>= 1) {
        if (threadIdx.x < st) {
            ls[threadIdx.x]  += ls[threadIdx.x + st];
            lss[threadIdx.x] += lss[threadIdx.x + st];
        }
        __syncthreads();
    }
    if (threadIdx.x == 0) {
        double mean = ls[0] / (double)NPIX;
        double var  = lss[0] / (double)NPIX - mean * mean;
        stats[oc]       = (float)mean;
        stats[256 + oc] = (float)(1.0 / sqrt(var + 1e-5));
    }
}

// ---------------- kernel 4: BN normalize + affine + SiLU (in-place) ----------------
__global__ __launch_bounds__(256) void k_bnsilu(float* __restrict__ out,
                                                const float* __restrict__ stats,
                                                const float* __restrict__ gamma,
                                                const float* __restrict__ beta)
{
    int n4 = (Bn * C2 * HWn) / 4;
    for (int i = blockIdx.x * blockDim.x + threadIdx.x; i < n4;
         i += gridDim.x * blockDim.x) {
        float4 v = ((float4*)out)[i];
        int e  = i * 4;
        int oc = (e / HWn) & 255;
        float mean = stats[oc];
        float gs   = gamma[oc] * stats[256 + oc];
        float bt   = beta[oc];
        float y;
        y = (v.x - mean) * gs + bt; v.x = y / (1.f + expf(-y));
        y = (v.y - mean) * gs + bt; v.y = y / (1.f + expf(-y));
        y = (v.z - mean) * gs + bt; v.z = y / (1.f + expf(-y));
        y = (v.w - mean) * gs + bt; v.w = y / (1.f + expf(-y));
        ((float4*)out)[i] = v;
    }
}

extern "C" void kernel_launch(void* const* d_in, const int* in_sizes, int n_in,
                              void* d_out, int out_size, void* d_ws, size_t ws_size,
                              hipStream_t stream)
{
    const float* x      = (const float*)d_in[0];
    const float* w_off  = (const float*)d_in[1];
    const float* b_off  = (const float*)d_in[2];
    const float* weight = (const float*)d_in[3];
    const float* bias   = (const float*)d_in[4];
    const float* gamma  = (const float*)d_in[5];
    const float* beta   = (const float*)d_in[6];
    float* out = (float*)d_out;

    // workspace layout (~229.3 MiB total)
    char* wsb = (char*)d_ws;
    unsigned short* Ahi = (unsigned short*)(wsb);                  // 117,964,800 B
    unsigned short* Alo = (unsigned short*)(wsb + 117964800);      // 117,964,800 B
    float*          off = (float*)(wsb + 235929600);               //   2,764,800 B
    unsigned short* wB1 = (unsigned short*)(wsb + 238694400);      //   1,474,560 B
    float*          wOT = (float*)(wsb + 240168960);               //     249,856 B
    float*        stats = (float*)(wsb + 240418816);               //       2,048 B

    k_wprep    <<<2880, 256, 0, stream>>>(weight, wB1);
    k_woprep   <<<244, 256, 0, stream>>>(w_off, wOT);
    k_offinit  <<<2700, 256, 0, stream>>>(b_off, off);
    k_offconv2 <<<800, 256, 0, stream>>>(x, wOT, off);
    k_gather   <<<28800, 256, 0, stream>>>(x, off, Ahi, Alo);
    k_dmfma    <<<800, 256, 0, stream>>>(Ahi, Alo, wB1, bias, out);
    k_bnstats  <<<256, 256, 0, stream>>>(out, stats);
    k_bnsilu   <<<2048, 256, 0, stream>>>(out, stats, gamma, beta);
}

// Round 12
// 459.212 us; speedup vs baseline: 1.5499x; 1.5499x over previous
//
#include <hip/hip_runtime.h>
#include <math.h>

constexpr int Hc = 80, Wc = 80, Bn = 4, C1 = 256, C2 = 256;
constexpr int HWn = Hc * Wc;          // 6400
constexpr int NPIX = Bn * HWn;        // 25600
constexpr int OFFC = 27;
constexpr int KK   = 2304;            // C1*9

typedef short bf16x8 __attribute__((ext_vector_type(8)));
typedef float f32x4  __attribute__((ext_vector_type(4)));

__device__ __forceinline__ unsigned f2bf(float f) {   // RNE to bf16 bits
    unsigned u = __float_as_uint(f);
    return (u + 0x7FFF + ((u >> 16) & 1)) >> 16;
}

// pack 2 floats -> hi-word (2 bf16) + lo-residual-word (2 bf16) via cvt_pk
__device__ __forceinline__ void pack2(float v0, float v1, unsigned& hw, unsigned& lw) {
    unsigned h;
    asm("v_cvt_pk_bf16_f32 %0, %1, %2" : "=v"(h) : "v"(v0), "v"(v1));
    float r0 = v0 - __uint_as_float(h << 16);
    float r1 = v1 - __uint_as_float(h & 0xffff0000u);
    unsigned l;
    asm("v_cvt_pk_bf16_f32 %0, %1, %2" : "=v"(l) : "v"(r0), "v"(r1));
    hw = h; lw = l;
}

// ---------------- kernel 0a: weight prep -> per-step B images (hi bf16 only) ----
// wB1[s][oc][40] bf16, s = p*8+cc (72 steps); kc<32 real, else pad 0
__global__ __launch_bounds__(256) void k_wprep(const float* __restrict__ weight,
                                               unsigned short* __restrict__ wB1)
{
    int e = blockIdx.x * 256 + threadIdx.x;   // 0 .. 737279
    int kc = e % 40;
    int oc = (e / 40) & 255;
    int s  = e / 10240;
    int p  = s >> 3, cc = s & 7;
    float w = 0.f;
    if (kc < 32) w = weight[((size_t)oc * C1 + cc * 32 + kc) * 9 + p];
    wB1[e] = (unsigned short)f2bf(w);
}

// ---------------- kernel 0b: offset-conv weight transpose -> wOT[c][244] -------
__global__ __launch_bounds__(256) void k_woprep(const float* __restrict__ w_off,
                                                float* __restrict__ wOT)
{
    int e = blockIdx.x * 256 + threadIdx.x;   // 0 .. 62463 (244 blocks)
    int c = e / 244, r = e - c * 244;
    float v = 0.f;
    if (r < 243) {
        int ch = r / 9, p = r - ch * 9;
        v = w_off[((size_t)ch * C1 + c) * 9 + p];
    }
    wOT[e] = v;
}

// ---------------- kernel 1a: init off buffer with b_off ----------------
__global__ __launch_bounds__(256) void k_offinit(const float* __restrict__ b_off,
                                                 float* __restrict__ off)
{
    int t = blockIdx.x * 256 + threadIdx.x;   // 0 .. 691199
    int ch = (t / HWn) % OFFC;
    off[t] = b_off[ch];
}

// ---------------- kernel 1b: offset conv v3 (LDS x-tile, unrolled reg weights) --
__global__ __launch_bounds__(256) void k_offconv2(const float* __restrict__ x,
                                                  const float* __restrict__ wOT,
                                                  float* __restrict__ off)
{
    __shared__ float xs[8][18][18];

    int tid  = threadIdx.x;
    int bidx = blockIdx.x;                 // 0..799
    int wt = bidx % 5;
    int ht = (bidx / 5) % 5;
    int b  = (bidx / 25) % 4;
    int cg = bidx / 100;                   // 0..7
    int h0 = ht * 16, w0 = wt * 16;
    int c0 = cg * 32;
    int ph = tid >> 4, pw = tid & 15;

    float acc[27];
    #pragma unroll
    for (int ch = 0; ch < 27; ++ch) acc[ch] = 0.f;

    const float* xb = x + (size_t)b * C1 * HWn;

    for (int cc = 0; cc < 4; ++cc) {       // 4 chunks of 8 channels
        __syncthreads();
        for (int idx = tid; idx < 8 * 324; idx += 256) {
            int cl  = idx / 324;
            int rem = idx - cl * 324;
            int r   = rem / 18;
            int col = rem - r * 18;
            int gh = h0 - 1 + r, gw = w0 - 1 + col;
            float v = 0.f;
            if (gh >= 0 && gh < Hc && gw >= 0 && gw < Wc)
                v = xb[(size_t)(c0 + cc * 8 + cl) * HWn + gh * Wc + gw];
            xs[cl][r][col] = v;
        }
        __syncthreads();
        #pragma unroll
        for (int cl = 0; cl < 8; ++cl) {
            float xr[9];
            #pragma unroll
            for (int kh = 0; kh < 3; ++kh)
                #pragma unroll
                for (int kw = 0; kw < 3; ++kw)
                    xr[kh * 3 + kw] = xs[cl][ph + kh][pw + kw];
            int c = c0 + cc * 8 + cl;
            const float4* wv4 = (const float4*)&wOT[c * 244];
            #pragma unroll
            for (int j = 0; j < 61; ++j) {
                float4 wj = wv4[j];
                #pragma unroll
                for (int u = 0; u < 4; ++u) {
                    constexpr int NW = 243;
                    int idx = 4 * j + u;
                    if (idx < NW)
                        acc[idx / 9] = fmaf(xr[idx % 9], (&wj.x)[u], acc[idx / 9]);
                }
            }
        }
    }

    int hw = (h0 + ph) * Wc + (w0 + pw);
    float* ob = off + (size_t)b * OFFC * HWn + hw;
    #pragma unroll
    for (int ch = 0; ch < 27; ++ch)
        atomicAdd(ob + (size_t)ch * HWn, acc[ch]);
}

// ---------------- kernel 1c: materialize masked bilinear patches v2 ----------------
// A layout is STEP-MAJOR: Ahi/Alo[72][NPIX][32] bf16 (step s = p*8 + c/32).
// Block = 64 px x 1 tap x 256 ch; LANE = PIXEL (round-11 fix: lanes along
// channels made every gather load touch 32-64 cache lines; lanes along
// near-consecutive pixels touch ~4-8 dense lines). Wave = 64-ch quarter.
// XCD-chunked 3600 = 8 x 450 (50 px-groups x 9 taps) -> XCD px-range matches
// k_dmfma's, x-slice 3.3MB L2-fit.
__global__ __launch_bounds__(256) void k_gather(const float* __restrict__ x,
                                                const float* __restrict__ off,
                                                unsigned short* __restrict__ Ahi,
                                                unsigned short* __restrict__ Alo)
{
    int q   = ((blockIdx.x & 7) * 450) + (blockIdx.x >> 3);
    int pxg = q / 9;
    int p   = q - pxg * 9;
    int t   = threadIdx.x;
    int pxo = t & 63;
    int chq = t >> 6;                   // wave = 64-channel quarter
    int px  = pxg * 64 + pxo;           // global pixel row
    int b   = px / HWn, hw = px - b * HWn;
    int h = hw / Wc, w = hw - h * Wc;
    int ii = p / 3, jj = p - ii * 3;

    const float* ob = off + (size_t)b * OFFC * HWn + hw;
    float dy = ob[(2 * p) * HWn];
    float dx = ob[(2 * p + 1) * HWn];
    float mv = ob[(18 + p) * HWn];
    float mask = 1.0f / (1.0f + expf(-mv));
    float ys = dy + (float)(h - 1 + ii);
    float xsv = dx + (float)(w - 1 + jj);
    float y0f = floorf(ys), x0f = floorf(xsv);
    float wy = ys - y0f, wx = xsv - x0f;
    int y0 = (int)y0f, x0 = (int)x0f;
    int y1 = y0 + 1, x1 = x0 + 1;
    float vy0 = (y0 >= 0 && y0 < Hc) ? 1.f : 0.f;
    float vy1 = (y1 >= 0 && y1 < Hc) ? 1.f : 0.f;
    float vx0 = (x0 >= 0 && x0 < Wc) ? 1.f : 0.f;
    float vx1 = (x1 >= 0 && x1 < Wc) ? 1.f : 0.f;
    float4 wv;
    wv.x = mask * (1.f - wy) * (1.f - wx) * vy0 * vx0;
    wv.y = mask * (1.f - wy) * wx         * vy0 * vx1;
    wv.z = mask * wy         * (1.f - wx) * vy1 * vx0;
    wv.w = mask * wy         * wx         * vy1 * vx1;
    int cy0 = min(max(y0, 0), Hc - 1), cy1 = min(max(y1, 0), Hc - 1);
    int cx0 = min(max(x0, 0), Wc - 1), cx1 = min(max(x1, 0), Wc - 1);
    int o00 = cy0 * Wc + cx0, o01 = cy0 * Wc + cx1;
    int o10 = cy1 * Wc + cx0, o11 = cy1 * Wc + cx1;

    const float* xb = x + (size_t)b * C1 * HWn;

    for (int cc = 0; cc < 8; ++cc) {        // 8 chunks of 8 channels
        int c0 = chq * 64 + cc * 8;
        const float* xc = xb + (size_t)c0 * HWn;
        float g00[8], g01[8], g10[8], g11[8];
        {
            unsigned co = 0;
            #pragma unroll
            for (int j = 0; j < 8; ++j) {
                g00[j] = xc[co + o00];
                g01[j] = xc[co + o01];
                g10[j] = xc[co + o10];
                g11[j] = xc[co + o11];
                co += HWn;
            }
        }
        float v[8];
        #pragma unroll
        for (int j = 0; j < 8; ++j)
            v[j] = fmaf(wv.x, g00[j], fmaf(wv.y, g01[j],
                   fmaf(wv.z, g10[j], wv.w * g11[j])));
        unsigned hu[4], lu[4];
        #pragma unroll
        for (int j = 0; j < 4; ++j) pack2(v[2 * j], v[2 * j + 1], hu[j], lu[j]);

        int s    = p * 8 + (c0 >> 5);       // step index
        int kcol = c0 & 31;                 // 0 or 8,16,24 within step
        size_t aidx = ((size_t)s * NPIX + px) * 32 + kcol;
        *(uint4*)&Ahi[aidx] = make_uint4(hu[0], hu[1], hu[2], hu[3]);
        *(uint4*)&Alo[aidx] = make_uint4(lu[0], lu[1], lu[2], lu[3]);
    }
}

// ------------- kernel 2: dense streaming MFMA GEMM v7 -------------
// A[72][NPIX][32] bf16 hi+lo planes (step-major -> loadA is one contiguous
// 1KB span per wave: 16 rows x 64B), B = wB1 per-step images.
// BM=32, BN=256, grid 800, XCD-chunked. 4 waves: (mi, nh) = 16px x 128oc.
// A-frags: direct global->VGPR dwordx4, 2-deep prefetch, 3-slot rotation.
// B: gll double-buffer. Raw s_barrier + counted vmcnt(2) (FIFO at wait:
// [gllB(s) x5, loadA(s+1) x2] -> drain own gll, keep A prefetch in flight);
// vmcnt(0) only at last step. LDS 40KB -> 4 blocks/CU.
__global__ __launch_bounds__(256, 4) void k_dmfma(const unsigned short* __restrict__ Ahi,
                                                  const unsigned short* __restrict__ Alo,
                                                  const unsigned short* __restrict__ wB1,
                                                  const float* __restrict__ bias,
                                                  float* __restrict__ out)
{
    __shared__ __align__(16) char smem[40960];   // B dbuf [2][256][40] u16
    float* Tb = (float*)smem;                    // epilogue alias [32][33] f32

    int t  = threadIdx.x;
    int wv = t >> 6, lane = t & 63;
    int li = lane & 15, kg = lane >> 4;
    int mi = wv & 1;                   // m-tile (16 px)
    int nh = wv >> 1;                  // oc 128-half

    int mtile = ((blockIdx.x & 7) * 100) + (blockIdx.x >> 3);
    int m0  = mtile * 32;
    int b   = m0 / HWn;
    int hw0 = m0 - b * HWn;
    int row = m0 + mi * 16 + li;

    auto gllB = [&](int s, int buf) {
        const char* src = (const char*)wB1 + (size_t)s * 20480 + wv * 5120 + lane * 16;
        char* dst = smem + buf * 20480 + wv * 5120;
        #pragma unroll
        for (int i = 0; i < 5; ++i)
            __builtin_amdgcn_global_load_lds(
                (const __attribute__((address_space(1))) void*)(src + i * 1024),
                (__attribute__((address_space(3))) void*)(dst + i * 1024),
                16, 0, 0);
    };
    auto loadA = [&](int s, uint4& hh, uint4& ll) {
        size_t base = ((size_t)s * NPIX + row) * 32 + kg * 8;
        hh = *(const uint4*)(Ahi + base);
        ll = *(const uint4*)(Alo + base);
    };

    f32x4 acc[8];
    #pragma unroll
    for (int n = 0; n < 8; ++n) acc[n] = (f32x4){0.f, 0.f, 0.f, 0.f};

    uint4 a0h, a0l, a1h, a1l, a2h, a2l;
    // prologue: A(0), gllB(0)->buf0, A(1)   [oldest-first so vmcnt(2) works at s=0]
    loadA(0, a0h, a0l);
    gllB(0, 0);
    loadA(1, a1h, a1l);

    auto step = [&](int s, uint4& ch, uint4& cl, uint4& lh, uint4& llo) {
        if (s == 71) { asm volatile("s_waitcnt vmcnt(0)" ::: "memory"); }
        else         { asm volatile("s_waitcnt vmcnt(2)" ::: "memory"); }
        __builtin_amdgcn_s_barrier();
        __builtin_amdgcn_sched_barrier(0);
        int cur = s & 1;
        if (s < 71) gllB(s + 1, cur ^ 1);
        __builtin_amdgcn_sched_barrier(0);
        if (s < 70) loadA(s + 2, lh, llo);
        __builtin_amdgcn_sched_barrier(0);
        const unsigned short* Bc = (const unsigned short*)(smem + cur * 20480);
        bf16x8 ah = __builtin_bit_cast(bf16x8, ch);
        bf16x8 al = __builtin_bit_cast(bf16x8, cl);
        __builtin_amdgcn_s_setprio(1);
        #pragma unroll
        for (int nt = 0; nt < 8; ++nt) {
            int oc = nh * 128 + nt * 16 + li;
            bf16x8 bv = *(const bf16x8*)&Bc[oc * 40 + kg * 8];
            acc[nt] = __builtin_amdgcn_mfma_f32_16x16x32_bf16(ah, bv, acc[nt], 0, 0, 0);
            acc[nt] = __builtin_amdgcn_mfma_f32_16x16x32_bf16(al, bv, acc[nt], 0, 0, 0);
        }
        __builtin_amdgcn_s_setprio(0);
    };

    for (int s = 0; s < 72; s += 3) {   // 3-slot rotation: consume / in-flight / load
        step(s,     a0h, a0l, a2h, a2l);
        step(s + 1, a1h, a1l, a0h, a0l);
        step(s + 2, a2h, a2l, a1h, a1l);
    }

    // ---- epilogue: 8 phases of 32 oc through Tb[32][33] ----
    // D frag: pixel = mi*16 + kg*4 + r ; oc = nh*128 + nt*16 + li
    #pragma unroll
    for (int q = 0; q < 8; ++q) {
        __syncthreads();
        if (nh == (q >> 2)) {
            #pragma unroll
            for (int j = 0; j < 2; ++j) {
                int nt = (q & 3) * 2 + j;
                f32x4 a = acc[nt];
                int rrw = j * 16 + li;              // oc row 0..31
                int col = mi * 16 + kg * 4;         // pixel col
                #pragma unroll
                for (int r = 0; r < 4; ++r)
                    Tb[rrw * 33 + col + r] = a[r];
            }
        }
        __syncthreads();
        int px = t & 31;
        int rw = t >> 5;                    // 0..7
        #pragma unroll
        for (int it = 0; it < 4; ++it) {
            int r  = it * 8 + rw;           // 0..31
            int oc = q * 32 + r;
            out[(size_t)(b * C2 + oc) * HWn + hw0 + px] = Tb[r * 33 + px] + bias[oc];
        }
    }
}

// ---------------- kernel 3: BN stats (per-channel mean, invstd) ----------------
__global__ __launch_bounds__(256) void k_bnstats(const float* __restrict__ out,
                                                 float* __restrict__ stats)
{
    int oc = blockIdx.x;
    double s = 0.0, ss = 0.0;
    for (int i = threadIdx.x; i < NPIX; i += 256) {
        int bb = i / HWn;
        int hw = i - bb * HWn;
        float v = out[(size_t)(bb * C2 + oc) * HWn + hw];
        s  += (double)v;
        ss += (double)v * (double)v;
    }
    __shared__ double ls[256], lss[256];
    ls[threadIdx.x] = s; lss[threadIdx.x] = ss;
    __syncthreads();
    for (int st = 128; st > 0; st >>= 1) {
        if (threadIdx.x < st) {
            ls[threadIdx.x]  += ls[threadIdx.x + st];
            lss[threadIdx.x] += lss[threadIdx.x + st];
        }
        __syncthreads();
    }
    if (threadIdx.x == 0) {
        double mean = ls[0] / (double)NPIX;
        double var  = lss[0] / (double)NPIX - mean * mean;
        stats[oc]       = (float)mean;
        stats[256 + oc] = (float)(1.0 / sqrt(var + 1e-5));
    }
}

// ---------------- kernel 4: BN normalize + affine + SiLU (in-place) ----------------
__global__ __launch_bounds__(256) void k_bnsilu(float* __restrict__ out,
                                                const float* __restrict__ stats,
                                                const float* __restrict__ gamma,
                                                const float* __restrict__ beta)
{
    int n4 = (Bn * C2 * HWn) / 4;
    for (int i = blockIdx.x * blockDim.x + threadIdx.x; i < n4;
         i += gridDim.x * blockDim.x) {
        float4 v = ((float4*)out)[i];
        int e  = i * 4;
        int oc = (e / HWn) & 255;
        float mean = stats[oc];
        float gs   = gamma[oc] * stats[256 + oc];
        float bt   = beta[oc];
        float y;
        y = (v.x - mean) * gs + bt; v.x = y / (1.f + expf(-y));
        y = (v.y - mean) * gs + bt; v.y = y / (1.f + expf(-y));
        y = (v.z - mean) * gs + bt; v.z = y / (1.f + expf(-y));
        y = (v.w - mean) * gs + bt; v.w = y / (1.f + expf(-y));
        ((float4*)out)[i] = v;
    }
}

extern "C" void kernel_launch(void* const* d_in, const int* in_sizes, int n_in,
                              void* d_out, int out_size, void* d_ws, size_t ws_size,
                              hipStream_t stream)
{
    const float* x      = (const float*)d_in[0];
    const float* w_off  = (const float*)d_in[1];
    const float* b_off  = (const float*)d_in[2];
    const float* weight = (const float*)d_in[3];
    const float* bias   = (const float*)d_in[4];
    const float* gamma  = (const float*)d_in[5];
    const float* beta   = (const float*)d_in[6];
    float* out = (float*)d_out;

    // workspace layout (~229.3 MiB total)
    char* wsb = (char*)d_ws;
    unsigned short* Ahi = (unsigned short*)(wsb);                  // 117,964,800 B
    unsigned short* Alo = (unsigned short*)(wsb + 117964800);      // 117,964,800 B
    float*          off = (float*)(wsb + 235929600);               //   2,764,800 B
    unsigned short* wB1 = (unsigned short*)(wsb + 238694400);      //   1,474,560 B
    float*          wOT = (float*)(wsb + 240168960);               //     249,856 B
    float*        stats = (float*)(wsb + 240418816);               //       2,048 B

    k_wprep    <<<2880, 256, 0, stream>>>(weight, wB1);
    k_woprep   <<<244, 256, 0, stream>>>(w_off, wOT);
    k_offinit  <<<2700, 256, 0, stream>>>(b_off, off);
    k_offconv2 <<<800, 256, 0, stream>>>(x, wOT, off);
    k_gather   <<<3600, 256, 0, stream>>>(x, off, Ahi, Alo);
    k_dmfma    <<<800, 256, 0, stream>>>(Ahi, Alo, wB1, bias, out);
    k_bnstats  <<<256, 256, 0, stream>>>(out, stats);
    k_bnsilu   <<<2048, 256, 0, stream>>>(out, stats, gamma, beta);
}

// Round 13
// 425.431 us; speedup vs baseline: 1.6729x; 1.0794x over previous
//
#include <hip/hip_runtime.h>
#include <math.h>

constexpr int Hc = 80, Wc = 80, Bn = 4, C1 = 256, C2 = 256;
constexpr int HWn = Hc * Wc;          // 6400
constexpr int NPIX = Bn * HWn;        // 25600
constexpr int OFFC = 27;
constexpr int KK   = 2304;            // C1*9

typedef short bf16x8 __attribute__((ext_vector_type(8)));
typedef float f32x4  __attribute__((ext_vector_type(4)));

__device__ __forceinline__ unsigned f2bf(float f) {   // RNE to bf16 bits
    unsigned u = __float_as_uint(f);
    return (u + 0x7FFF + ((u >> 16) & 1)) >> 16;
}

// pack 2 floats -> hi-word (2 bf16) + lo-residual-word (2 bf16) via cvt_pk
__device__ __forceinline__ void pack2(float v0, float v1, unsigned& hw, unsigned& lw) {
    unsigned h;
    asm("v_cvt_pk_bf16_f32 %0, %1, %2" : "=v"(h) : "v"(v0), "v"(v1));
    float r0 = v0 - __uint_as_float(h << 16);
    float r1 = v1 - __uint_as_float(h & 0xffff0000u);
    unsigned l;
    asm("v_cvt_pk_bf16_f32 %0, %1, %2" : "=v"(l) : "v"(r0), "v"(r1));
    hw = h; lw = l;
}

// ---------------- kernel 0a: weight prep -> per-step B images (hi bf16 only) ----
// wB1[s][oc][40] bf16, s = p*8+cc (72 steps); kc<32 real, else pad 0
__global__ __launch_bounds__(256) void k_wprep(const float* __restrict__ weight,
                                               unsigned short* __restrict__ wB1)
{
    int e = blockIdx.x * 256 + threadIdx.x;   // 0 .. 737279
    int kc = e % 40;
    int oc = (e / 40) & 255;
    int s  = e / 10240;
    int p  = s >> 3, cc = s & 7;
    float w = 0.f;
    if (kc < 32) w = weight[((size_t)oc * C1 + cc * 32 + kc) * 9 + p];
    wB1[e] = (unsigned short)f2bf(w);
}

// ---------------- kernel 0b: offset-conv weight transpose -> wOT[c][244] -------
__global__ __launch_bounds__(256) void k_woprep(const float* __restrict__ w_off,
                                                float* __restrict__ wOT)
{
    int e = blockIdx.x * 256 + threadIdx.x;   // 0 .. 62463 (244 blocks)
    int c = e / 244, r = e - c * 244;
    float v = 0.f;
    if (r < 243) {
        int ch = r / 9, p = r - ch * 9;
        v = w_off[((size_t)ch * C1 + c) * 9 + p];
    }
    wOT[e] = v;
}

// ---------------- kernel 1a: init off buffer with b_off ----------------
__global__ __launch_bounds__(256) void k_offinit(const float* __restrict__ b_off,
                                                 float* __restrict__ off)
{
    int t = blockIdx.x * 256 + threadIdx.x;   // 0 .. 691199
    int ch = (t / HWn) % OFFC;
    off[t] = b_off[ch];
}

// ---------------- kernel 1b: offset conv v3 (LDS x-tile, unrolled reg weights) --
__global__ __launch_bounds__(256) void k_offconv2(const float* __restrict__ x,
                                                  const float* __restrict__ wOT,
                                                  float* __restrict__ off)
{
    __shared__ float xs[8][18][18];

    int tid  = threadIdx.x;
    int bidx = blockIdx.x;                 // 0..799
    int wt = bidx % 5;
    int ht = (bidx / 5) % 5;
    int b  = (bidx / 25) % 4;
    int cg = bidx / 100;                   // 0..7
    int h0 = ht * 16, w0 = wt * 16;
    int c0 = cg * 32;
    int ph = tid >> 4, pw = tid & 15;

    float acc[27];
    #pragma unroll
    for (int ch = 0; ch < 27; ++ch) acc[ch] = 0.f;

    const float* xb = x + (size_t)b * C1 * HWn;

    for (int cc = 0; cc < 4; ++cc) {       // 4 chunks of 8 channels
        __syncthreads();
        for (int idx = tid; idx < 8 * 324; idx += 256) {
            int cl  = idx / 324;
            int rem = idx - cl * 324;
            int r   = rem / 18;
            int col = rem - r * 18;
            int gh = h0 - 1 + r, gw = w0 - 1 + col;
            float v = 0.f;
            if (gh >= 0 && gh < Hc && gw >= 0 && gw < Wc)
                v = xb[(size_t)(c0 + cc * 8 + cl) * HWn + gh * Wc + gw];
            xs[cl][r][col] = v;
        }
        __syncthreads();
        #pragma unroll
        for (int cl = 0; cl < 8; ++cl) {
            float xr[9];
            #pragma unroll
            for (int kh = 0; kh < 3; ++kh)
                #pragma unroll
                for (int kw = 0; kw < 3; ++kw)
                    xr[kh * 3 + kw] = xs[cl][ph + kh][pw + kw];
            int c = c0 + cc * 8 + cl;
            const float4* wv4 = (const float4*)&wOT[c * 244];
            #pragma unroll
            for (int j = 0; j < 61; ++j) {
                float4 wj = wv4[j];
                #pragma unroll
                for (int u = 0; u < 4; ++u) {
                    constexpr int NW = 243;
                    int idx = 4 * j + u;
                    if (idx < NW)
                        acc[idx / 9] = fmaf(xr[idx % 9], (&wj.x)[u], acc[idx / 9]);
                }
            }
        }
    }

    int hw = (h0 + ph) * Wc + (w0 + pw);
    float* ob = off + (size_t)b * OFFC * HWn + hw;
    #pragma unroll
    for (int ch = 0; ch < 27; ++ch)
        atomicAdd(ob + (size_t)ch * HWn, acc[ch]);
}

// ---------------- kernel 1c: materialize masked bilinear patches v3 ----------------
// A layout STEP-MAJOR: Ahi/Alo[72][NPIX][32] bf16 (step s = p*8 + c/32).
// round-12 fix: lane = (px_local<<2)|kq -> each wave's 16B/lane stores cover
// one CONTIGUOUS 1KB span (round-12 counters: lane=pixel gave 64B-stride
// stores -> 365MB written vs 236MB ideal, write-transaction bound).
// Each thread gathers 8 channels (kq*8..+7) of one step for its pixel.
// Reads: 16px x 4 planes per load instr - slightly more lines, but x is
// L2-resident (FETCH 19MB) and L2 BW has huge headroom.
// XCD-chunked 3600 = 8 x 450 (50 px-groups x 9 taps).
__global__ __launch_bounds__(256) void k_gather(const float* __restrict__ x,
                                                const float* __restrict__ off,
                                                unsigned short* __restrict__ Ahi,
                                                unsigned short* __restrict__ Alo)
{
    int q   = ((blockIdx.x & 7) * 450) + (blockIdx.x >> 3);
    int pxg = q / 9;
    int p   = q - pxg * 9;
    int t   = threadIdx.x;
    int l   = t & 63;
    int wvq = t >> 6;                   // wave = 16-pixel group
    int kq  = l & 3;                    // k-quad (8 channels)
    int pxo = l >> 2;                   // pixel within wave 0..15
    int px  = pxg * 64 + wvq * 16 + pxo;
    int b   = px / HWn, hw = px - b * HWn;
    int h = hw / Wc, w = hw - h * Wc;
    int ii = p / 3, jj = p - ii * 3;

    const float* ob = off + (size_t)b * OFFC * HWn + hw;
    float dy = ob[(2 * p) * HWn];
    float dx = ob[(2 * p + 1) * HWn];
    float mv = ob[(18 + p) * HWn];
    float mask = 1.0f / (1.0f + expf(-mv));
    float ys = dy + (float)(h - 1 + ii);
    float xsv = dx + (float)(w - 1 + jj);
    float y0f = floorf(ys), x0f = floorf(xsv);
    float wy = ys - y0f, wx = xsv - x0f;
    int y0 = (int)y0f, x0 = (int)x0f;
    int y1 = y0 + 1, x1 = x0 + 1;
    float vy0 = (y0 >= 0 && y0 < Hc) ? 1.f : 0.f;
    float vy1 = (y1 >= 0 && y1 < Hc) ? 1.f : 0.f;
    float vx0 = (x0 >= 0 && x0 < Wc) ? 1.f : 0.f;
    float vx1 = (x1 >= 0 && x1 < Wc) ? 1.f : 0.f;
    float4 wv;
    wv.x = mask * (1.f - wy) * (1.f - wx) * vy0 * vx0;
    wv.y = mask * (1.f - wy) * wx         * vy0 * vx1;
    wv.z = mask * wy         * (1.f - wx) * vy1 * vx0;
    wv.w = mask * wy         * wx         * vy1 * vx1;
    int cy0 = min(max(y0, 0), Hc - 1), cy1 = min(max(y1, 0), Hc - 1);
    int cx0 = min(max(x0, 0), Wc - 1), cx1 = min(max(x1, 0), Wc - 1);
    int o00 = cy0 * Wc + cx0, o01 = cy0 * Wc + cx1;
    int o10 = cy1 * Wc + cx0, o11 = cy1 * Wc + cx1;

    const float* xb = x + (size_t)b * C1 * HWn;

    for (int cc = 0; cc < 8; ++cc) {        // step s = p*8 + cc
        int c0 = cc * 32 + kq * 8;          // this thread's 8 channels
        const float* xc = xb + (size_t)c0 * HWn;
        float g00[8], g01[8], g10[8], g11[8];
        {
            unsigned co = 0;
            #pragma unroll
            for (int j = 0; j < 8; ++j) {
                g00[j] = xc[co + o00];
                g01[j] = xc[co + o01];
                g10[j] = xc[co + o10];
                g11[j] = xc[co + o11];
                co += HWn;
            }
        }
        float v[8];
        #pragma unroll
        for (int j = 0; j < 8; ++j)
            v[j] = fmaf(wv.x, g00[j], fmaf(wv.y, g01[j],
                   fmaf(wv.z, g10[j], wv.w * g11[j])));
        unsigned hu[4], lu[4];
        #pragma unroll
        for (int j = 0; j < 4; ++j) pack2(v[2 * j], v[2 * j + 1], hu[j], lu[j]);

        int s = p * 8 + cc;
        size_t aidx = ((size_t)s * NPIX + px) * 32 + kq * 8;
        *(uint4*)&Ahi[aidx] = make_uint4(hu[0], hu[1], hu[2], hu[3]);
        *(uint4*)&Alo[aidx] = make_uint4(lu[0], lu[1], lu[2], lu[3]);
    }
}

// ------------- kernel 2: dense streaming MFMA GEMM v7 -------------
// A[72][NPIX][32] bf16 hi+lo planes (step-major -> loadA is one contiguous
// 1KB span per wave: 16 rows x 64B), B = wB1 per-step images.
// BM=32, BN=256, grid 800, XCD-chunked. 4 waves: (mi, nh) = 16px x 128oc.
// A-frags: direct global->VGPR dwordx4, 2-deep prefetch, 3-slot rotation.
// B: gll double-buffer. Raw s_barrier + counted vmcnt(2) (FIFO at wait:
// [gllB(s) x5, loadA(s+1) x2] -> drain own gll, keep A prefetch in flight);
// vmcnt(0) only at last step. LDS 40KB -> 4 blocks/CU.
__global__ __launch_bounds__(256, 4) void k_dmfma(const unsigned short* __restrict__ Ahi,
                                                  const unsigned short* __restrict__ Alo,
                                                  const unsigned short* __restrict__ wB1,
                                                  const float* __restrict__ bias,
                                                  float* __restrict__ out)
{
    __shared__ __align__(16) char smem[40960];   // B dbuf [2][256][40] u16
    float* Tb = (float*)smem;                    // epilogue alias [32][33] f32

    int t  = threadIdx.x;
    int wv = t >> 6, lane = t & 63;
    int li = lane & 15, kg = lane >> 4;
    int mi = wv & 1;                   // m-tile (16 px)
    int nh = wv >> 1;                  // oc 128-half

    int mtile = ((blockIdx.x & 7) * 100) + (blockIdx.x >> 3);
    int m0  = mtile * 32;
    int b   = m0 / HWn;
    int hw0 = m0 - b * HWn;
    int row = m0 + mi * 16 + li;

    auto gllB = [&](int s, int buf) {
        const char* src = (const char*)wB1 + (size_t)s * 20480 + wv * 5120 + lane * 16;
        char* dst = smem + buf * 20480 + wv * 5120;
        #pragma unroll
        for (int i = 0; i < 5; ++i)
            __builtin_amdgcn_global_load_lds(
                (const __attribute__((address_space(1))) void*)(src + i * 1024),
                (__attribute__((address_space(3))) void*)(dst + i * 1024),
                16, 0, 0);
    };
    auto loadA = [&](int s, uint4& hh, uint4& ll) {
        size_t base = ((size_t)s * NPIX + row) * 32 + kg * 8;
        hh = *(const uint4*)(Ahi + base);
        ll = *(const uint4*)(Alo + base);
    };

    f32x4 acc[8];
    #pragma unroll
    for (int n = 0; n < 8; ++n) acc[n] = (f32x4){0.f, 0.f, 0.f, 0.f};

    uint4 a0h, a0l, a1h, a1l, a2h, a2l;
    // prologue: A(0), gllB(0)->buf0, A(1)   [oldest-first so vmcnt(2) works at s=0]
    loadA(0, a0h, a0l);
    gllB(0, 0);
    loadA(1, a1h, a1l);

    auto step = [&](int s, uint4& ch, uint4& cl, uint4& lh, uint4& llo) {
        if (s == 71) { asm volatile("s_waitcnt vmcnt(0)" ::: "memory"); }
        else         { asm volatile("s_waitcnt vmcnt(2)" ::: "memory"); }
        __builtin_amdgcn_s_barrier();
        __builtin_amdgcn_sched_barrier(0);
        int cur = s & 1;
        if (s < 71) gllB(s + 1, cur ^ 1);
        __builtin_amdgcn_sched_barrier(0);
        if (s < 70) loadA(s + 2, lh, llo);
        __builtin_amdgcn_sched_barrier(0);
        const unsigned short* Bc = (const unsigned short*)(smem + cur * 20480);
        bf16x8 ah = __builtin_bit_cast(bf16x8, ch);
        bf16x8 al = __builtin_bit_cast(bf16x8, cl);
        __builtin_amdgcn_s_setprio(1);
        #pragma unroll
        for (int nt = 0; nt < 8; ++nt) {
            int oc = nh * 128 + nt * 16 + li;
            bf16x8 bv = *(const bf16x8*)&Bc[oc * 40 + kg * 8];
            acc[nt] = __builtin_amdgcn_mfma_f32_16x16x32_bf16(ah, bv, acc[nt], 0, 0, 0);
            acc[nt] = __builtin_amdgcn_mfma_f32_16x16x32_bf16(al, bv, acc[nt], 0, 0, 0);
        }
        __builtin_amdgcn_s_setprio(0);
    };

    for (int s = 0; s < 72; s += 3) {   // 3-slot rotation: consume / in-flight / load
        step(s,     a0h, a0l, a2h, a2l);
        step(s + 1, a1h, a1l, a0h, a0l);
        step(s + 2, a2h, a2l, a1h, a1l);
    }

    // ---- epilogue: 8 phases of 32 oc through Tb[32][33] ----
    // D frag: pixel = mi*16 + kg*4 + r ; oc = nh*128 + nt*16 + li
    #pragma unroll
    for (int q = 0; q < 8; ++q) {
        __syncthreads();
        if (nh == (q >> 2)) {
            #pragma unroll
            for (int j = 0; j < 2; ++j) {
                int nt = (q & 3) * 2 + j;
                f32x4 a = acc[nt];
                int rrw = j * 16 + li;              // oc row 0..31
                int col = mi * 16 + kg * 4;         // pixel col
                #pragma unroll
                for (int r = 0; r < 4; ++r)
                    Tb[rrw * 33 + col + r] = a[r];
            }
        }
        __syncthreads();
        int px = t & 31;
        int rw = t >> 5;                    // 0..7
        #pragma unroll
        for (int it = 0; it < 4; ++it) {
            int r  = it * 8 + rw;           // 0..31
            int oc = q * 32 + r;
            out[(size_t)(b * C2 + oc) * HWn + hw0 + px] = Tb[r * 33 + px] + bias[oc];
        }
    }
}

// ---------------- kernel 3: BN stats (per-channel mean, invstd) ----------------
__global__ __launch_bounds__(256) void k_bnstats(const float* __restrict__ out,
                                                 float* __restrict__ stats)
{
    int oc = blockIdx.x;
    double s = 0.0, ss = 0.0;
    for (int i = threadIdx.x; i < NPIX; i += 256) {
        int bb = i / HWn;
        int hw = i - bb * HWn;
        float v = out[(size_t)(bb * C2 + oc) * HWn + hw];
        s  += (double)v;
        ss += (double)v * (double)v;
    }
    __shared__ double ls[256], lss[256];
    ls[threadIdx.x] = s; lss[threadIdx.x] = ss;
    __syncthreads();
    for (int st = 128; st > 0; st >>= 1) {
        if (threadIdx.x < st) {
            ls[threadIdx.x]  += ls[threadIdx.x + st];
            lss[threadIdx.x] += lss[threadIdx.x + st];
        }
        __syncthreads();
    }
    if (threadIdx.x == 0) {
        double mean = ls[0] / (double)NPIX;
        double var  = lss[0] / (double)NPIX - mean * mean;
        stats[oc]       = (float)mean;
        stats[256 + oc] = (float)(1.0 / sqrt(var + 1e-5));
    }
}

// ---------------- kernel 4: BN normalize + affine + SiLU (in-place) ----------------
__global__ __launch_bounds__(256) void k_bnsilu(float* __restrict__ out,
                                                const float* __restrict__ stats,
                                                const float* __restrict__ gamma,
                                                const float* __restrict__ beta)
{
    int n4 = (Bn * C2 * HWn) / 4;
    for (int i = blockIdx.x * blockDim.x + threadIdx.x; i < n4;
         i += gridDim.x * blockDim.x) {
        float4 v = ((float4*)out)[i];
        int e  = i * 4;
        int oc = (e / HWn) & 255;
        float mean = stats[oc];
        float gs   = gamma[oc] * stats[256 + oc];
        float bt   = beta[oc];
        float y;
        y = (v.x - mean) * gs + bt; v.x = y / (1.f + expf(-y));
        y = (v.y - mean) * gs + bt; v.y = y / (1.f + expf(-y));
        y = (v.z - mean) * gs + bt; v.z = y / (1.f + expf(-y));
        y = (v.w - mean) * gs + bt; v.w = y / (1.f + expf(-y));
        ((float4*)out)[i] = v;
    }
}

extern "C" void kernel_launch(void* const* d_in, const int* in_sizes, int n_in,
                              void* d_out, int out_size, void* d_ws, size_t ws_size,
                              hipStream_t stream)
{
    const float* x      = (const float*)d_in[0];
    const float* w_off  = (const float*)d_in[1];
    const float* b_off  = (const float*)d_in[2];
    const float* weight = (const float*)d_in[3];
    const float* bias   = (const float*)d_in[4];
    const float* gamma  = (const float*)d_in[5];
    const float* beta   = (const float*)d_in[6];
    float* out = (float*)d_out;

    // workspace layout (~229.3 MiB total)
    char* wsb = (char*)d_ws;
    unsigned short* Ahi = (unsigned short*)(wsb);                  // 117,964,800 B
    unsigned short* Alo = (unsigned short*)(wsb + 117964800);      // 117,964,800 B
    float*          off = (float*)(wsb + 235929600);               //   2,764,800 B
    unsigned short* wB1 = (unsigned short*)(wsb + 238694400);      //   1,474,560 B
    float*          wOT = (float*)(wsb + 240168960);               //     249,856 B
    float*        stats = (float*)(wsb + 240418816);               //       2,048 B

    k_wprep    <<<2880, 256, 0, stream>>>(weight, wB1);
    k_woprep   <<<244, 256, 0, stream>>>(w_off, wOT);
    k_offinit  <<<2700, 256, 0, stream>>>(b_off, off);
    k_offconv2 <<<800, 256, 0, stream>>>(x, wOT, off);
    k_gather   <<<3600, 256, 0, stream>>>(x, off, Ahi, Alo);
    k_dmfma    <<<800, 256, 0, stream>>>(Ahi, Alo, wB1, bias, out);
    k_bnstats  <<<256, 256, 0, stream>>>(out, stats);
    k_bnsilu   <<<2048, 256, 0, stream>>>(out, stats, gamma, beta);
}

// Round 14
// 379.690 us; speedup vs baseline: 1.8745x; 1.1205x over previous
//
#include <hip/hip_runtime.h>
#include <math.h>

constexpr int Hc = 80, Wc = 80, Bn = 4, C1 = 256, C2 = 256;
constexpr int HWn = Hc * Wc;          // 6400
constexpr int NPIX = Bn * HWn;        // 25600
constexpr int OFFC = 27;
constexpr int KK   = 2304;            // C1*9

typedef short bf16x8 __attribute__((ext_vector_type(8)));
typedef float f32x4  __attribute__((ext_vector_type(4)));

__device__ __forceinline__ unsigned f2bf(float f) {   // RNE to bf16 bits
    unsigned u = __float_as_uint(f);
    return (u + 0x7FFF + ((u >> 16) & 1)) >> 16;
}

// pack 2 floats -> 1 u32 of 2 bf16 via cvt_pk (RNE)
__device__ __forceinline__ unsigned packhi2(float v0, float v1) {
    unsigned h;
    asm("v_cvt_pk_bf16_f32 %0, %1, %2" : "=v"(h) : "v"(v0), "v"(v1));
    return h;
}

// ---------------- kernel 0a: weight prep -> per-step B images (hi bf16 only) ----
// wB1[s][oc][40] bf16, s = p*8+cc (72 steps); kc<32 real, else pad 0
__global__ __launch_bounds__(256) void k_wprep(const float* __restrict__ weight,
                                               unsigned short* __restrict__ wB1)
{
    int e = blockIdx.x * 256 + threadIdx.x;   // 0 .. 737279
    int kc = e % 40;
    int oc = (e / 40) & 255;
    int s  = e / 10240;
    int p  = s >> 3, cc = s & 7;
    float w = 0.f;
    if (kc < 32) w = weight[((size_t)oc * C1 + cc * 32 + kc) * 9 + p];
    wB1[e] = (unsigned short)f2bf(w);
}

// ---------------- kernel 0b: offset-conv weight transpose -> wOT[c][244] -------
__global__ __launch_bounds__(256) void k_woprep(const float* __restrict__ w_off,
                                                float* __restrict__ wOT)
{
    int e = blockIdx.x * 256 + threadIdx.x;   // 0 .. 62463 (244 blocks)
    int c = e / 244, r = e - c * 244;
    float v = 0.f;
    if (r < 243) {
        int ch = r / 9, p = r - ch * 9;
        v = w_off[((size_t)ch * C1 + c) * 9 + p];
    }
    wOT[e] = v;
}

// ---------------- kernel 1a: init off buffer with b_off ----------------
__global__ __launch_bounds__(256) void k_offinit(const float* __restrict__ b_off,
                                                 float* __restrict__ off)
{
    int t = blockIdx.x * 256 + threadIdx.x;   // 0 .. 691199
    int ch = (t / HWn) % OFFC;
    off[t] = b_off[ch];
}

// ---------------- kernel 1b: offset conv v3 (LDS x-tile, unrolled reg weights) --
__global__ __launch_bounds__(256) void k_offconv2(const float* __restrict__ x,
                                                  const float* __restrict__ wOT,
                                                  float* __restrict__ off)
{
    __shared__ float xs[8][18][18];

    int tid  = threadIdx.x;
    int bidx = blockIdx.x;                 // 0..799
    int wt = bidx % 5;
    int ht = (bidx / 5) % 5;
    int b  = (bidx / 25) % 4;
    int cg = bidx / 100;                   // 0..7
    int h0 = ht * 16, w0 = wt * 16;
    int c0 = cg * 32;
    int ph = tid >> 4, pw = tid & 15;

    float acc[27];
    #pragma unroll
    for (int ch = 0; ch < 27; ++ch) acc[ch] = 0.f;

    const float* xb = x + (size_t)b * C1 * HWn;

    for (int cc = 0; cc < 4; ++cc) {       // 4 chunks of 8 channels
        __syncthreads();
        for (int idx = tid; idx < 8 * 324; idx += 256) {
            int cl  = idx / 324;
            int rem = idx - cl * 324;
            int r   = rem / 18;
            int col = rem - r * 18;
            int gh = h0 - 1 + r, gw = w0 - 1 + col;
            float v = 0.f;
            if (gh >= 0 && gh < Hc && gw >= 0 && gw < Wc)
                v = xb[(size_t)(c0 + cc * 8 + cl) * HWn + gh * Wc + gw];
            xs[cl][r][col] = v;
        }
        __syncthreads();
        #pragma unroll
        for (int cl = 0; cl < 8; ++cl) {
            float xr[9];
            #pragma unroll
            for (int kh = 0; kh < 3; ++kh)
                #pragma unroll
                for (int kw = 0; kw < 3; ++kw)
                    xr[kh * 3 + kw] = xs[cl][ph + kh][pw + kw];
            int c = c0 + cc * 8 + cl;
            const float4* wv4 = (const float4*)&wOT[c * 244];
            #pragma unroll
            for (int j = 0; j < 61; ++j) {
                float4 wj = wv4[j];
                #pragma unroll
                for (int u = 0; u < 4; ++u) {
                    constexpr int NW = 243;
                    int idx = 4 * j + u;
                    if (idx < NW)
                        acc[idx / 9] = fmaf(xr[idx % 9], (&wj.x)[u], acc[idx / 9]);
                }
            }
        }
    }

    int hw = (h0 + ph) * Wc + (w0 + pw);
    float* ob = off + (size_t)b * OFFC * HWn + hw;
    #pragma unroll
    for (int ch = 0; ch < 27; ++ch)
        atomicAdd(ob + (size_t)ch * HWn, acc[ch]);
}

// ---------------- kernel 1c: materialize masked bilinear patches v4 ----------------
// A layout STEP-MAJOR, BF16-ONLY (round-13 lever: dropped the lo-residual
// plane; error budget ~1e-3 post-BN std, adds in quadrature with B-bf16's
// 0.031 absmax -> predicted ~0.05 < 0.1075 threshold). Halves gather writes,
// dmfma A-stream, and MFMA count.
// Ahi[72][NPIX][32] bf16; lane = (px_local<<2)|kq -> wave stores = one
// contiguous 1KB span. XCD-chunked 3600 = 8 x 450.
__global__ __launch_bounds__(256) void k_gather(const float* __restrict__ x,
                                                const float* __restrict__ off,
                                                unsigned short* __restrict__ Ahi)
{
    int q   = ((blockIdx.x & 7) * 450) + (blockIdx.x >> 3);
    int pxg = q / 9;
    int p   = q - pxg * 9;
    int t   = threadIdx.x;
    int l   = t & 63;
    int wvq = t >> 6;                   // wave = 16-pixel group
    int kq  = l & 3;                    // k-quad (8 channels)
    int pxo = l >> 2;                   // pixel within wave 0..15
    int px  = pxg * 64 + wvq * 16 + pxo;
    int b   = px / HWn, hw = px - b * HWn;
    int h = hw / Wc, w = hw - h * Wc;
    int ii = p / 3, jj = p - ii * 3;

    const float* ob = off + (size_t)b * OFFC * HWn + hw;
    float dy = ob[(2 * p) * HWn];
    float dx = ob[(2 * p + 1) * HWn];
    float mv = ob[(18 + p) * HWn];
    float mask = 1.0f / (1.0f + expf(-mv));
    float ys = dy + (float)(h - 1 + ii);
    float xsv = dx + (float)(w - 1 + jj);
    float y0f = floorf(ys), x0f = floorf(xsv);
    float wy = ys - y0f, wx = xsv - x0f;
    int y0 = (int)y0f, x0 = (int)x0f;
    int y1 = y0 + 1, x1 = x0 + 1;
    float vy0 = (y0 >= 0 && y0 < Hc) ? 1.f : 0.f;
    float vy1 = (y1 >= 0 && y1 < Hc) ? 1.f : 0.f;
    float vx0 = (x0 >= 0 && x0 < Wc) ? 1.f : 0.f;
    float vx1 = (x1 >= 0 && x1 < Wc) ? 1.f : 0.f;
    float4 wv;
    wv.x = mask * (1.f - wy) * (1.f - wx) * vy0 * vx0;
    wv.y = mask * (1.f - wy) * wx         * vy0 * vx1;
    wv.z = mask * wy         * (1.f - wx) * vy1 * vx0;
    wv.w = mask * wy         * wx         * vy1 * vx1;
    int cy0 = min(max(y0, 0), Hc - 1), cy1 = min(max(y1, 0), Hc - 1);
    int cx0 = min(max(x0, 0), Wc - 1), cx1 = min(max(x1, 0), Wc - 1);
    int o00 = cy0 * Wc + cx0, o01 = cy0 * Wc + cx1;
    int o10 = cy1 * Wc + cx0, o11 = cy1 * Wc + cx1;

    const float* xb = x + (size_t)b * C1 * HWn;

    for (int cc = 0; cc < 8; ++cc) {        // step s = p*8 + cc
        int c0 = cc * 32 + kq * 8;          // this thread's 8 channels
        const float* xc = xb + (size_t)c0 * HWn;
        float g00[8], g01[8], g10[8], g11[8];
        {
            unsigned co = 0;
            #pragma unroll
            for (int j = 0; j < 8; ++j) {
                g00[j] = xc[co + o00];
                g01[j] = xc[co + o01];
                g10[j] = xc[co + o10];
                g11[j] = xc[co + o11];
                co += HWn;
            }
        }
        float v[8];
        #pragma unroll
        for (int j = 0; j < 8; ++j)
            v[j] = fmaf(wv.x, g00[j], fmaf(wv.y, g01[j],
                   fmaf(wv.z, g10[j], wv.w * g11[j])));
        unsigned hu[4];
        #pragma unroll
        for (int j = 0; j < 4; ++j) hu[j] = packhi2(v[2 * j], v[2 * j + 1]);

        int s = p * 8 + cc;
        size_t aidx = ((size_t)s * NPIX + px) * 32 + kq * 8;
        *(uint4*)&Ahi[aidx] = make_uint4(hu[0], hu[1], hu[2], hu[3]);
    }
}

// ------------- kernel 2: dense streaming MFMA GEMM v8 (A bf16-only) -------------
// A[72][NPIX][32] bf16 (step-major -> loadA = one contiguous 1KB span/wave),
// B = wB1 per-step images. BM=32, BN=256, grid 800, XCD-chunked.
// 4 waves: (mi, nh) = 16px x 128oc. A direct global->VGPR dwordx4, 2-deep
// prefetch, 3-slot rotation. B gll double-buffer. Raw s_barrier + counted
// vmcnt(1): FIFO at wait = [gllB(s) x5, loadA(s+1) x1] -> drain own gll,
// keep the 1 A-prefetch in flight (count re-derived for 1-op loadA; was
// vmcnt(2) with the 2-op hi+lo loadA). Prologue [A(0) x1, gllB(0) x5,
// A(1) x1] -> vmcnt(1) drains buf0 exactly. vmcnt(0) only at last step.
// LDS 40KB -> 4 blocks/CU. 8 MFMA/step (halved with A-lo drop).
__global__ __launch_bounds__(256, 4) void k_dmfma(const unsigned short* __restrict__ Ahi,
                                                  const unsigned short* __restrict__ wB1,
                                                  const float* __restrict__ bias,
                                                  float* __restrict__ out)
{
    __shared__ __align__(16) char smem[40960];   // B dbuf [2][256][40] u16
    float* Tb = (float*)smem;                    // epilogue alias [32][33] f32

    int t  = threadIdx.x;
    int wv = t >> 6, lane = t & 63;
    int li = lane & 15, kg = lane >> 4;
    int mi = wv & 1;                   // m-tile (16 px)
    int nh = wv >> 1;                  // oc 128-half

    int mtile = ((blockIdx.x & 7) * 100) + (blockIdx.x >> 3);
    int m0  = mtile * 32;
    int b   = m0 / HWn;
    int hw0 = m0 - b * HWn;
    int row = m0 + mi * 16 + li;

    auto gllB = [&](int s, int buf) {
        const char* src = (const char*)wB1 + (size_t)s * 20480 + wv * 5120 + lane * 16;
        char* dst = smem + buf * 20480 + wv * 5120;
        #pragma unroll
        for (int i = 0; i < 5; ++i)
            __builtin_amdgcn_global_load_lds(
                (const __attribute__((address_space(1))) void*)(src + i * 1024),
                (__attribute__((address_space(3))) void*)(dst + i * 1024),
                16, 0, 0);
    };
    auto loadA = [&](int s, uint4& hh) {
        size_t base = ((size_t)s * NPIX + row) * 32 + kg * 8;
        hh = *(const uint4*)(Ahi + base);
    };

    f32x4 acc[8];
    #pragma unroll
    for (int n = 0; n < 8; ++n) acc[n] = (f32x4){0.f, 0.f, 0.f, 0.f};

    uint4 a0h, a1h, a2h;
    // prologue: A(0), gllB(0)->buf0, A(1)   [oldest-first so vmcnt(1) works at s=0]
    loadA(0, a0h);
    gllB(0, 0);
    loadA(1, a1h);

    auto step = [&](int s, uint4& ch, uint4& lh) {
        if (s == 71) { asm volatile("s_waitcnt vmcnt(0)" ::: "memory"); }
        else         { asm volatile("s_waitcnt vmcnt(1)" ::: "memory"); }
        __builtin_amdgcn_s_barrier();
        __builtin_amdgcn_sched_barrier(0);
        int cur = s & 1;
        if (s < 71) gllB(s + 1, cur ^ 1);
        __builtin_amdgcn_sched_barrier(0);
        if (s < 70) loadA(s + 2, lh);
        __builtin_amdgcn_sched_barrier(0);
        const unsigned short* Bc = (const unsigned short*)(smem + cur * 20480);
        bf16x8 ah = __builtin_bit_cast(bf16x8, ch);
        __builtin_amdgcn_s_setprio(1);
        #pragma unroll
        for (int nt = 0; nt < 8; ++nt) {
            int oc = nh * 128 + nt * 16 + li;
            bf16x8 bv = *(const bf16x8*)&Bc[oc * 40 + kg * 8];
            acc[nt] = __builtin_amdgcn_mfma_f32_16x16x32_bf16(ah, bv, acc[nt], 0, 0, 0);
        }
        __builtin_amdgcn_s_setprio(0);
    };

    for (int s = 0; s < 72; s += 3) {   // 3-slot rotation: consume / in-flight / load
        step(s,     a0h, a2h);
        step(s + 1, a1h, a0h);
        step(s + 2, a2h, a1h);
    }

    // ---- epilogue: 8 phases of 32 oc through Tb[32][33] ----
    // D frag: pixel = mi*16 + kg*4 + r ; oc = nh*128 + nt*16 + li
    #pragma unroll
    for (int q = 0; q < 8; ++q) {
        __syncthreads();
        if (nh == (q >> 2)) {
            #pragma unroll
            for (int j = 0; j < 2; ++j) {
                int nt = (q & 3) * 2 + j;
                f32x4 a = acc[nt];
                int rrw = j * 16 + li;              // oc row 0..31
                int col = mi * 16 + kg * 4;         // pixel col
                #pragma unroll
                for (int r = 0; r < 4; ++r)
                    Tb[rrw * 33 + col + r] = a[r];
            }
        }
        __syncthreads();
        int px = t & 31;
        int rw = t >> 5;                    // 0..7
        #pragma unroll
        for (int it = 0; it < 4; ++it) {
            int r  = it * 8 + rw;           // 0..31
            int oc = q * 32 + r;
            out[(size_t)(b * C2 + oc) * HWn + hw0 + px] = Tb[r * 33 + px] + bias[oc];
        }
    }
}

// ---------------- kernel 3: BN stats (per-channel mean, invstd) ----------------
__global__ __launch_bounds__(256) void k_bnstats(const float* __restrict__ out,
                                                 float* __restrict__ stats)
{
    int oc = blockIdx.x;
    double s = 0.0, ss = 0.0;
    for (int i = threadIdx.x; i < NPIX; i += 256) {
        int bb = i / HWn;
        int hw = i - bb * HWn;
        float v = out[(size_t)(bb * C2 + oc) * HWn + hw];
        s  += (double)v;
        ss += (double)v * (double)v;
    }
    __shared__ double ls[256], lss[256];
    ls[threadIdx.x] = s; lss[threadIdx.x] = ss;
    __syncthreads();
    for (int st = 128; st > 0; st >>= 1) {
        if (threadIdx.x < st) {
            ls[threadIdx.x]  += ls[threadIdx.x + st];
            lss[threadIdx.x] += lss[threadIdx.x + st];
        }
        __syncthreads();
    }
    if (threadIdx.x == 0) {
        double mean = ls[0] / (double)NPIX;
        double var  = lss[0] / (double)NPIX - mean * mean;
        stats[oc]       = (float)mean;
        stats[256 + oc] = (float)(1.0 / sqrt(var + 1e-5));
    }
}

// ---------------- kernel 4: BN normalize + affine + SiLU (in-place) ----------------
__global__ __launch_bounds__(256) void k_bnsilu(float* __restrict__ out,
                                                const float* __restrict__ stats,
                                                const float* __restrict__ gamma,
                                                const float* __restrict__ beta)
{
    int n4 = (Bn * C2 * HWn) / 4;
    for (int i = blockIdx.x * blockDim.x + threadIdx.x; i < n4;
         i += gridDim.x * blockDim.x) {
        float4 v = ((float4*)out)[i];
        int e  = i * 4;
        int oc = (e / HWn) & 255;
        float mean = stats[oc];
        float gs   = gamma[oc] * stats[256 + oc];
        float bt   = beta[oc];
        float y;
        y = (v.x - mean) * gs + bt; v.x = y / (1.f + expf(-y));
        y = (v.y - mean) * gs + bt; v.y = y / (1.f + expf(-y));
        y = (v.z - mean) * gs + bt; v.z = y / (1.f + expf(-y));
        y = (v.w - mean) * gs + bt; v.w = y / (1.f + expf(-y));
        ((float4*)out)[i] = v;
    }
}

extern "C" void kernel_launch(void* const* d_in, const int* in_sizes, int n_in,
                              void* d_out, int out_size, void* d_ws, size_t ws_size,
                              hipStream_t stream)
{
    const float* x      = (const float*)d_in[0];
    const float* w_off  = (const float*)d_in[1];
    const float* b_off  = (const float*)d_in[2];
    const float* weight = (const float*)d_in[3];
    const float* bias   = (const float*)d_in[4];
    const float* gamma  = (const float*)d_in[5];
    const float* beta   = (const float*)d_in[6];
    float* out = (float*)d_out;

    // workspace layout (~115 MiB total)
    char* wsb = (char*)d_ws;
    unsigned short* Ahi = (unsigned short*)(wsb);                  // 117,964,800 B
    float*          off = (float*)(wsb + 117964800);               //   2,764,800 B
    unsigned short* wB1 = (unsigned short*)(wsb + 120729600);      //   1,474,560 B
    float*          wOT = (float*)(wsb + 122204160);               //     249,856 B
    float*        stats = (float*)(wsb + 122454016);               //       2,048 B

    k_wprep    <<<2880, 256, 0, stream>>>(weight, wB1);
    k_woprep   <<<244, 256, 0, stream>>>(w_off, wOT);
    k_offinit  <<<2700, 256, 0, stream>>>(b_off, off);
    k_offconv2 <<<800, 256, 0, stream>>>(x, wOT, off);
    k_gather   <<<3600, 256, 0, stream>>>(x, off, Ahi);
    k_dmfma    <<<800, 256, 0, stream>>>(Ahi, wB1, bias, out);
    k_bnstats  <<<256, 256, 0, stream>>>(out, stats);
    k_bnsilu   <<<2048, 256, 0, stream>>>(out, stats, gamma, beta);
}

// Round 17
// 316.345 us; speedup vs baseline: 2.2498x; 1.2002x over previous
//
#include <hip/hip_runtime.h>
#include <math.h>

constexpr int Hc = 80, Wc = 80, Bn = 4, C1 = 256, C2 = 256;
constexpr int HWn = Hc * Wc;          // 6400
constexpr int NPIX = Bn * HWn;        // 25600
constexpr int OFFC = 27;
constexpr int KK   = 2304;            // C1*9
constexpr int NPAIR = NPIX * 9;       // 230400

typedef short bf16x8 __attribute__((ext_vector_type(8)));
typedef float f32x4  __attribute__((ext_vector_type(4)));

__device__ __forceinline__ unsigned f2bf(float f) {   // RNE to bf16 bits
    unsigned u = __float_as_uint(f);
    return (u + 0x7FFF + ((u >> 16) & 1)) >> 16;
}

// pack 2 floats -> 1 u32 of 2 bf16 via cvt_pk (RNE)
__device__ __forceinline__ unsigned packhi2(float v0, float v1) {
    unsigned h;
    asm("v_cvt_pk_bf16_f32 %0, %1, %2" : "=v"(h) : "v"(v0), "v"(v1));
    return h;
}

// ---------------- kernel 0a: weight prep -> per-step B images (hi bf16 only) ----
__global__ __launch_bounds__(256) void k_wprep(const float* __restrict__ weight,
                                               unsigned short* __restrict__ wB1)
{
    int e = blockIdx.x * 256 + threadIdx.x;   // 0 .. 737279
    int kc = e % 40;
    int oc = (e / 40) & 255;
    int s  = e / 10240;
    int p  = s >> 3, cc = s & 7;
    float w = 0.f;
    if (kc < 32) w = weight[((size_t)oc * C1 + cc * 32 + kc) * 9 + p];
    wB1[e] = (unsigned short)f2bf(w);
}

// ---------------- kernel 0b: offset-conv weight transpose -> wOT[c][244] -------
__global__ __launch_bounds__(256) void k_woprep(const float* __restrict__ w_off,
                                                float* __restrict__ wOT)
{
    int e = blockIdx.x * 256 + threadIdx.x;   // 0 .. 62463 (244 blocks)
    int c = e / 244, r = e - c * 244;
    float v = 0.f;
    if (r < 243) {
        int ch = r / 9, p = r - ch * 9;
        v = w_off[((size_t)ch * C1 + c) * 9 + p];
    }
    wOT[e] = v;
}

// ---------------- kernel 0c: x transpose -> xT[b][hw][c] ----------------
// LDS 32x32 tile transpose (+1 pad), both sides coalesced. 6400 blocks.
__global__ __launch_bounds__(256) void k_xtrans(const float* __restrict__ x,
                                                float* __restrict__ xT)
{
    __shared__ float tile[32][33];
    int bid = blockIdx.x;                 // b*(200*8) + hwt*8 + ct
    int ct  = bid & 7;
    int hwt = (bid >> 3) % 200;
    int b   = bid / 1600;
    int c0  = ct * 32, hw0 = hwt * 32;
    int tid = threadIdx.x;
    int col = tid & 31, rw = tid >> 5;    // 8 rows per pass
    const float* xb = x + (size_t)b * C1 * HWn;
    #pragma unroll
    for (int k = 0; k < 4; ++k) {
        int r = rw + k * 8;               // c-index
        tile[r][col] = xb[(size_t)(c0 + r) * HWn + hw0 + col];
    }
    __syncthreads();
    float* xo = xT + ((size_t)b * HWn + hw0) * C1 + c0;
    #pragma unroll
    for (int k = 0; k < 4; ++k) {
        int r = rw + k * 8;               // hw-index
        xo[(size_t)r * C1 + col] = tile[col][r];
    }
}

// ---------------- kernel 1a: init off buffer with b_off ----------------
__global__ __launch_bounds__(256) void k_offinit(const float* __restrict__ b_off,
                                                 float* __restrict__ off)
{
    int t = blockIdx.x * 256 + threadIdx.x;   // 0 .. 691199
    int ch = (t / HWn) % OFFC;
    off[t] = b_off[ch];
}

// ---------------- kernel 1b: offset conv v3 (LDS x-tile, unrolled reg weights) --
__global__ __launch_bounds__(256) void k_offconv2(const float* __restrict__ x,
                                                  const float* __restrict__ wOT,
                                                  float* __restrict__ off)
{
    __shared__ float xs[8][18][18];

    int tid  = threadIdx.x;
    int bidx = blockIdx.x;                 // 0..799
    int wt = bidx % 5;
    int ht = (bidx / 5) % 5;
    int b  = (bidx / 25) % 4;
    int cg = bidx / 100;                   // 0..7
    int h0 = ht * 16, w0 = wt * 16;
    int c0 = cg * 32;
    int ph = tid >> 4, pw = tid & 15;

    float acc[27];
    #pragma unroll
    for (int ch = 0; ch < 27; ++ch) acc[ch] = 0.f;

    const float* xb = x + (size_t)b * C1 * HWn;

    for (int cc = 0; cc < 4; ++cc) {       // 4 chunks of 8 channels
        __syncthreads();
        for (int idx = tid; idx < 8 * 324; idx += 256) {
            int cl  = idx / 324;
            int rem = idx - cl * 324;
            int r   = rem / 18;
            int col = rem - r * 18;
            int gh = h0 - 1 + r, gw = w0 - 1 + col;
            float v = 0.f;
            if (gh >= 0 && gh < Hc && gw >= 0 && gw < Wc)
                v = xb[(size_t)(c0 + cc * 8 + cl) * HWn + gh * Wc + gw];
            xs[cl][r][col] = v;
        }
        __syncthreads();
        #pragma unroll
        for (int cl = 0; cl < 8; ++cl) {
            float xr[9];
            #pragma unroll
            for (int kh = 0; kh < 3; ++kh)
                #pragma unroll
                for (int kw = 0; kw < 3; ++kw)
                    xr[kh * 3 + kw] = xs[cl][ph + kh][pw + kw];
            int c = c0 + cc * 8 + cl;
            const float4* wv4 = (const float4*)&wOT[c * 244];
            #pragma unroll
            for (int j = 0; j < 61; ++j) {
                float4 wj = wv4[j];
                #pragma unroll
                for (int u = 0; u < 4; ++u) {
                    constexpr int NW = 243;
                    int idx = 4 * j + u;
                    if (idx < NW)
                        acc[idx / 9] = fmaf(xr[idx % 9], (&wj.x)[u], acc[idx / 9]);
                }
            }
        }
    }

    int hw = (h0 + ph) * Wc + (w0 + pw);
    float* ob = off + (size_t)b * OFFC * HWn + hw;
    #pragma unroll
    for (int ch = 0; ch < 27; ++ch)
        atomicAdd(ob + (size_t)ch * HWn, acc[ch]);
}

// ---------------- kernel 1c-pre: bilinear metadata table ----------------
// Per (px, tap): crd (4x u8) + 4 fused weights. 900 blocks.
__global__ __launch_bounds__(256) void k_meta(const float* __restrict__ off,
                                              int* __restrict__ crdbuf,
                                              float4* __restrict__ w4buf)
{
    int pair = blockIdx.x * 256 + threadIdx.x;   // 0 .. 230399
    int px = pair / 9, p = pair - px * 9;
    int b  = px / HWn, hw = px - b * HWn;
    int h = hw / Wc, w = hw - h * Wc;
    int ii = p / 3, jj = p - ii * 3;

    const float* ob = off + (size_t)b * OFFC * HWn + hw;
    float dy = ob[(2 * p) * HWn];
    float dx = ob[(2 * p + 1) * HWn];
    float mv = ob[(18 + p) * HWn];
    float mask = 1.0f / (1.0f + expf(-mv));
    float ys = dy + (float)(h - 1 + ii);
    float xsv = dx + (float)(w - 1 + jj);
    float y0f = floorf(ys), x0f = floorf(xsv);
    float wy = ys - y0f, wx = xsv - x0f;
    int y0 = (int)y0f, x0 = (int)x0f;
    int y1 = y0 + 1, x1 = x0 + 1;
    float vy0 = (y0 >= 0 && y0 < Hc) ? 1.f : 0.f;
    float vy1 = (y1 >= 0 && y1 < Hc) ? 1.f : 0.f;
    float vx0 = (x0 >= 0 && x0 < Wc) ? 1.f : 0.f;
    float vx1 = (x1 >= 0 && x1 < Wc) ? 1.f : 0.f;
    float4 wv;
    wv.x = mask * (1.f - wy) * (1.f - wx) * vy0 * vx0;
    wv.y = mask * (1.f - wy) * wx         * vy0 * vx1;
    wv.z = mask * wy         * (1.f - wx) * vy1 * vx0;
    wv.w = mask * wy         * wx         * vy1 * vx1;
    int cy0 = min(max(y0, 0), Hc - 1), cy1 = min(max(y1, 0), Hc - 1);
    int cx0 = min(max(x0, 0), Wc - 1), cx1 = min(max(x1, 0), Wc - 1);
    crdbuf[pair] = cy0 | (cy1 << 8) | (cx0 << 16) | (cx1 << 24);
    w4buf[pair]  = wv;
}

// ---------------- kernel 1c: materialize patches v5 (channel-dense reads) -------
// round-14 fix: gather was READ-transaction-bound (write halving didn't move
// dur; 790 GB/s, VALU 14%) — corner reads spanned 4 channel planes 25.6KB
// apart. Now: wave = ONE (px,tap) pair, lane = 4 channels; corner read =
// xT[o*256 + 4*lane] -> one dense 1KB dwordx4 wave-load; 4 loads/pair.
// Store: ch=4l -> s = p*8 + (l>>3), kcol = 4*(l&7): 8 lanes per 64B line,
// full lines. 800 blocks XCD-chunked: waves [k*400,(k+1)*400) own pairs
// [k*28800, ...) = px range [k*3200, ...) matching dmfma's chunking.
__global__ __launch_bounds__(256) void k_gather(const float* __restrict__ xT,
                                                const int* __restrict__ crdbuf,
                                                const float4* __restrict__ w4buf,
                                                unsigned short* __restrict__ Ahi)
{
    int t   = threadIdx.x;
    int wv  = t >> 6, l = t & 63;
    int xcd = blockIdx.x & 7;
    int blk = blockIdx.x >> 3;               // 0..99 within XCD
    int wgl = (xcd * 100 + blk) * 4 + wv;    // global wave 0..3199
    int base = wgl * 72;

    #pragma unroll 2
    for (int i = 0; i < 72; ++i) {
        int pair = base + i;
        int px = pair / 9, p = pair - px * 9;
        int b  = px / HWn;
        int crd = crdbuf[pair];
        float4 w4 = w4buf[pair];
        int cy0 = crd & 255, cy1 = (crd >> 8) & 255;
        int cx0 = (crd >> 16) & 255, cx1 = (crd >> 24) & 255;
        const float* xt = xT + (size_t)b * HWn * C1;
        const float4* g00p = (const float4*)&xt[(size_t)(cy0 * Wc + cx0) * C1];
        const float4* g01p = (const float4*)&xt[(size_t)(cy0 * Wc + cx1) * C1];
        const float4* g10p = (const float4*)&xt[(size_t)(cy1 * Wc + cx0) * C1];
        const float4* g11p = (const float4*)&xt[(size_t)(cy1 * Wc + cx1) * C1];
        float4 g00 = g00p[l], g01 = g01p[l], g10 = g10p[l], g11 = g11p[l];
        float vx = fmaf(w4.x, g00.x, fmaf(w4.y, g01.x, fmaf(w4.z, g10.x, w4.w * g11.x)));
        float vy = fmaf(w4.x, g00.y, fmaf(w4.y, g01.y, fmaf(w4.z, g10.y, w4.w * g11.y)));
        float vz = fmaf(w4.x, g00.z, fmaf(w4.y, g01.z, fmaf(w4.z, g10.z, w4.w * g11.z)));
        float vw = fmaf(w4.x, g00.w, fmaf(w4.y, g01.w, fmaf(w4.z, g10.w, w4.w * g11.w)));
        unsigned h0 = packhi2(vx, vy), h1 = packhi2(vz, vw);
        // ch = 4l -> step s = p*8 + (l>>3), col = 4*(l&7)
        int s = p * 8 + (l >> 3);
        size_t aidx = ((size_t)s * NPIX + px) * 32 + 4 * (l & 7);
        *(uint2*)&Ahi[aidx] = make_uint2(h0, h1);
    }
}

// ------------- kernel 2: dense streaming MFMA GEMM v8 (A bf16-only) -------------
// (unchanged from round 13 — vmcnt(1) protocol, see comment)
__global__ __launch_bounds__(256, 4) void k_dmfma(const unsigned short* __restrict__ Ahi,
                                                  const unsigned short* __restrict__ wB1,
                                                  const float* __restrict__ bias,
                                                  float* __restrict__ out)
{
    __shared__ __align__(16) char smem[40960];   // B dbuf [2][256][40] u16
    float* Tb = (float*)smem;                    // epilogue alias [32][33] f32

    int t  = threadIdx.x;
    int wv = t >> 6, lane = t & 63;
    int li = lane & 15, kg = lane >> 4;
    int mi = wv & 1;                   // m-tile (16 px)
    int nh = wv >> 1;                  // oc 128-half

    int mtile = ((blockIdx.x & 7) * 100) + (blockIdx.x >> 3);
    int m0  = mtile * 32;
    int b   = m0 / HWn;
    int hw0 = m0 - b * HWn;
    int row = m0 + mi * 16 + li;

    auto gllB = [&](int s, int buf) {
        const char* src = (const char*)wB1 + (size_t)s * 20480 + wv * 5120 + lane * 16;
        char* dst = smem + buf * 20480 + wv * 5120;
        #pragma unroll
        for (int i = 0; i < 5; ++i)
            __builtin_amdgcn_global_load_lds(
                (const __attribute__((address_space(1))) void*)(src + i * 1024),
                (__attribute__((address_space(3))) void*)(dst + i * 1024),
                16, 0, 0);
    };
    auto loadA = [&](int s, uint4& hh) {
        size_t base = ((size_t)s * NPIX + row) * 32 + kg * 8;
        hh = *(const uint4*)(Ahi + base);
    };

    f32x4 acc[8];
    #pragma unroll
    for (int n = 0; n < 8; ++n) acc[n] = (f32x4){0.f, 0.f, 0.f, 0.f};

    uint4 a0h, a1h, a2h;
    loadA(0, a0h);
    gllB(0, 0);
    loadA(1, a1h);

    auto step = [&](int s, uint4& ch, uint4& lh) {
        if (s == 71) { asm volatile("s_waitcnt vmcnt(0)" ::: "memory"); }
        else         { asm volatile("s_waitcnt vmcnt(1)" ::: "memory"); }
        __builtin_amdgcn_s_barrier();
        __builtin_amdgcn_sched_barrier(0);
        int cur = s & 1;
        if (s < 71) gllB(s + 1, cur ^ 1);
        __builtin_amdgcn_sched_barrier(0);
        if (s < 70) loadA(s + 2, lh);
        __builtin_amdgcn_sched_barrier(0);
        const unsigned short* Bc = (const unsigned short*)(smem + cur * 20480);
        bf16x8 ah = __builtin_bit_cast(bf16x8, ch);
        __builtin_amdgcn_s_setprio(1);
        #pragma unroll
        for (int nt = 0; nt < 8; ++nt) {
            int oc = nh * 128 + nt * 16 + li;
            bf16x8 bv = *(const bf16x8*)&Bc[oc * 40 + kg * 8];
            acc[nt] = __builtin_amdgcn_mfma_f32_16x16x32_bf16(ah, bv, acc[nt], 0, 0, 0);
        }
        __builtin_amdgcn_s_setprio(0);
    };

    for (int s = 0; s < 72; s += 3) {   // 3-slot rotation
        step(s,     a0h, a2h);
        step(s + 1, a1h, a0h);
        step(s + 2, a2h, a1h);
    }

    // ---- epilogue: 8 phases of 32 oc through Tb[32][33] ----
    #pragma unroll
    for (int q = 0; q < 8; ++q) {
        __syncthreads();
        if (nh == (q >> 2)) {
            #pragma unroll
            for (int j = 0; j < 2; ++j) {
                int nt = (q & 3) * 2 + j;
                f32x4 a = acc[nt];
                int rrw = j * 16 + li;              // oc row 0..31
                int col = mi * 16 + kg * 4;         // pixel col
                #pragma unroll
                for (int r = 0; r < 4; ++r)
                    Tb[rrw * 33 + col + r] = a[r];
            }
        }
        __syncthreads();
        int px = t & 31;
        int rw = t >> 5;                    // 0..7
        #pragma unroll
        for (int it = 0; it < 4; ++it) {
            int r  = it * 8 + rw;           // 0..31
            int oc = q * 32 + r;
            out[(size_t)(b * C2 + oc) * HWn + hw0 + px] = Tb[r * 33 + px] + bias[oc];
        }
    }
}

// ---------------- kernel 3: BN stats (per-channel mean, invstd) ----------------
__global__ __launch_bounds__(256) void k_bnstats(const float* __restrict__ out,
                                                 float* __restrict__ stats)
{
    int oc = blockIdx.x;
    double s = 0.0, ss = 0.0;
    for (int i = threadIdx.x; i < NPIX; i += 256) {
        int bb = i / HWn;
        int hw = i - bb * HWn;
        float v = out[(size_t)(bb * C2 + oc) * HWn + hw];
        s  += (double)v;
        ss += (double)v * (double)v;
    }
    __shared__ double ls[256], lss[256];
    ls[threadIdx.x] = s; lss[threadIdx.x] = ss;
    __syncthreads();
    for (int st = 128; st > 0; st >>= 1) {
        if (threadIdx.x < st) {
            ls[threadIdx.x]  += ls[threadIdx.x + st];
            lss[threadIdx.x] += lss[threadIdx.x + st];
        }
        __syncthreads();
    }
    if (threadIdx.x == 0) {
        double mean = ls[0] / (double)NPIX;
        double var  = lss[0] / (double)NPIX - mean * mean;
        stats[oc]       = (float)mean;
        stats[256 + oc] = (float)(1.0 / sqrt(var + 1e-5));
    }
}

// ---------------- kernel 4: BN normalize + affine + SiLU (in-place) ----------------
__global__ __launch_bounds__(256) void k_bnsilu(float* __restrict__ out,
                                                const float* __restrict__ stats,
                                                const float* __restrict__ gamma,
                                                const float* __restrict__ beta)
{
    int n4 = (Bn * C2 * HWn) / 4;
    for (int i = blockIdx.x * blockDim.x + threadIdx.x; i < n4;
         i += gridDim.x * blockDim.x) {
        float4 v = ((float4*)out)[i];
        int e  = i * 4;
        int oc = (e / HWn) & 255;
        float mean = stats[oc];
        float gs   = gamma[oc] * stats[256 + oc];
        float bt   = beta[oc];
        float y;
        y = (v.x - mean) * gs + bt; v.x = y / (1.f + expf(-y));
        y = (v.y - mean) * gs + bt; v.y = y / (1.f + expf(-y));
        y = (v.z - mean) * gs + bt; v.z = y / (1.f + expf(-y));
        y = (v.w - mean) * gs + bt; v.w = y / (1.f + expf(-y));
        ((float4*)out)[i] = v;
    }
}

extern "C" void kernel_launch(void* const* d_in, const int* in_sizes, int n_in,
                              void* d_out, int out_size, void* d_ws, size_t ws_size,
                              hipStream_t stream)
{
    const float* x      = (const float*)d_in[0];
    const float* w_off  = (const float*)d_in[1];
    const float* b_off  = (const float*)d_in[2];
    const float* weight = (const float*)d_in[3];
    const float* bias   = (const float*)d_in[4];
    const float* gamma  = (const float*)d_in[5];
    const float* beta   = (const float*)d_in[6];
    float* out = (float*)d_out;

    // workspace layout (~155 MiB total)
    char* wsb = (char*)d_ws;
    unsigned short* Ahi  = (unsigned short*)(wsb);                 // 117,964,800 B
    float*          xT   = (float*)(wsb + 117964800);              //  26,214,400 B
    float*          off  = (float*)(wsb + 144179200);              //   2,764,800 B
    unsigned short* wB1  = (unsigned short*)(wsb + 146944000);     //   1,474,560 B
    float*          wOT  = (float*)(wsb + 148418560);              //     249,856 B
    int*            crdb = (int*)(wsb + 148668416);                //     921,600 B
    float4*         w4b  = (float4*)(wsb + 149590016);             //   3,686,400 B
    float*         stats = (float*)(wsb + 153276416);              //       2,048 B

    k_wprep    <<<2880, 256, 0, stream>>>(weight, wB1);
    k_woprep   <<<244, 256, 0, stream>>>(w_off, wOT);
    k_xtrans   <<<6400, 256, 0, stream>>>(x, xT);
    k_offinit  <<<2700, 256, 0, stream>>>(b_off, off);
    k_offconv2 <<<800, 256, 0, stream>>>(x, wOT, off);
    k_meta     <<<900, 256, 0, stream>>>(off, crdb, w4b);
    k_gather   <<<800, 256, 0, stream>>>(xT, crdb, w4b, Ahi);
    k_dmfma    <<<800, 256, 0, stream>>>(Ahi, wB1, bias, out);
    k_bnstats  <<<256, 256, 0, stream>>>(out, stats);
    k_bnsilu   <<<2048, 256, 0, stream>>>(out, stats, gamma, beta);
}

// Round 18
// 250.737 us; speedup vs baseline: 2.8385x; 1.2617x over previous
//
#include <hip/hip_runtime.h>
#include <math.h>

constexpr int Hc = 80, Wc = 80, Bn = 4, C1 = 256, C2 = 256;
constexpr int HWn = Hc * Wc;          // 6400
constexpr int NPIX = Bn * HWn;        // 25600
constexpr int OFFC = 27;
constexpr int KK   = 2304;            // C1*9

typedef short bf16x8 __attribute__((ext_vector_type(8)));
typedef float f32x4  __attribute__((ext_vector_type(4)));

__device__ __forceinline__ unsigned f2bf(float f) {   // RNE to bf16 bits
    unsigned u = __float_as_uint(f);
    return (u + 0x7FFF + ((u >> 16) & 1)) >> 16;
}

// pack 2 floats -> 1 u32 of 2 bf16 via cvt_pk (RNE)
__device__ __forceinline__ unsigned packhi2(float v0, float v1) {
    unsigned h;
    asm("v_cvt_pk_bf16_f32 %0, %1, %2" : "=v"(h) : "v"(v0), "v"(v1));
    return h;
}

// ---------------- kernel 0a: weight prep -> per-step B images (hi bf16 only) ----
__global__ __launch_bounds__(256) void k_wprep(const float* __restrict__ weight,
                                               unsigned short* __restrict__ wB1)
{
    int e = blockIdx.x * 256 + threadIdx.x;   // 0 .. 737279
    int kc = e % 40;
    int oc = (e / 40) & 255;
    int s  = e / 10240;
    int p  = s >> 3, cc = s & 7;
    float w = 0.f;
    if (kc < 32) w = weight[((size_t)oc * C1 + cc * 32 + kc) * 9 + p];
    wB1[e] = (unsigned short)f2bf(w);
}

// ---------------- kernel 0b: offset-conv MFMA weight prep -> wOB[s][32][32] ----
// wOB[s][oc][k] bf16, s = p*8+cc; oc<27 real else 0. 288 blocks = 73728 elems.
__global__ __launch_bounds__(256) void k_wobprep(const float* __restrict__ w_off,
                                                 unsigned short* __restrict__ wOB)
{
    int e = blockIdx.x * 256 + threadIdx.x;   // 0 .. 73727
    int k  = e & 31;
    int oc = (e >> 5) & 31;
    int s  = e >> 10;                         // 0..71
    int p  = s >> 3, cc = s & 7;
    float v = 0.f;
    if (oc < 27) v = w_off[((size_t)oc * C1 + cc * 32 + k) * 9 + p];
    wOB[e] = (unsigned short)f2bf(v);
}

// ---------------- kernel 0c: x transpose -> xT[b][hw][c] (f32) + xTb (bf16) ----
// LDS 32x32 tile transpose (+1 pad), both sides coalesced. 6400 blocks.
__global__ __launch_bounds__(256) void k_xtrans(const float* __restrict__ x,
                                                float* __restrict__ xT,
                                                unsigned short* __restrict__ xTb)
{
    __shared__ float tile[32][33];
    int bid = blockIdx.x;                 // b*(200*8) + hwt*8 + ct
    int ct  = bid & 7;
    int hwt = (bid >> 3) % 200;
    int b   = bid / 1600;
    int c0  = ct * 32, hw0 = hwt * 32;
    int tid = threadIdx.x;
    int col = tid & 31, rw = tid >> 5;    // 8 rows per pass
    const float* xb = x + (size_t)b * C1 * HWn;
    #pragma unroll
    for (int k = 0; k < 4; ++k) {
        int r = rw + k * 8;               // c-index
        tile[r][col] = xb[(size_t)(c0 + r) * HWn + hw0 + col];
    }
    __syncthreads();
    float* xo = xT + ((size_t)b * HWn + hw0) * C1 + c0;
    unsigned short* xob = xTb + ((size_t)b * HWn + hw0) * C1 + c0;
    #pragma unroll
    for (int k = 0; k < 4; ++k) {
        int r = rw + k * 8;               // hw-index
        float v = tile[col][r];
        xo[(size_t)r * C1 + col]  = v;
        xob[(size_t)r * C1 + col] = (unsigned short)f2bf(v);
    }
}

// ---------------- kernel 1b: offset conv v4 — MFMA, no LDS, no barriers --------
// round-17 diagnosis: offconv2 was scalar-load-latency bound (119us, VALU 23%).
// It IS a GEMM: M=25600px (9 integer taps), N=27(pad 32), K=2304. Structure:
// block = 32px x 32oc, 4 waves (mi,nj) of 16x16; per step (p,cc): 1 A-dwordx4
// from xTb (bf16, channel-dense), 1 B-dwordx4 from wOB (147KB, L1/L2-hit),
// 1 MFMA. 72 free-running steps; border taps zero-filled via lane select.
// Writes off directly (+b_off bias) -> k_offinit deleted. Fragment and store
// mappings mirror the verified k_dmfma conventions.
__global__ __launch_bounds__(256) void k_offmfma(const unsigned short* __restrict__ xTb,
                                                 const unsigned short* __restrict__ wOB,
                                                 const float* __restrict__ b_off,
                                                 float* __restrict__ off)
{
    int t  = threadIdx.x;
    int wv = t >> 6, lane = t & 63;
    int li = lane & 15, kg = lane >> 4;
    int mi = wv & 1;                   // m-tile (16 px)
    int nj = wv >> 1;                  // n-tile (16 oc)

    int mtile = ((blockIdx.x & 7) * 100) + (blockIdx.x >> 3);
    int m0  = mtile * 32;
    int b   = m0 / HWn;                // uniform per block
    int hw0 = m0 - b * HWn;
    int pxl = hw0 + mi * 16 + li;      // this lane's hw (A row)
    int h = pxl / Wc, w = pxl - h * Wc;

    const unsigned short* xb = xTb + (size_t)b * HWn * C1;

    f32x4 acc = (f32x4){0.f, 0.f, 0.f, 0.f};
    #pragma unroll
    for (int p = 0; p < 9; ++p) {
        int dh = p / 3 - 1, dw = p % 3 - 1;
        int hh = h + dh, ww = w + dw;
        bool valid = (hh >= 0 && hh < Hc && ww >= 0 && ww < Wc);
        int hwp = valid ? (hh * Wc + ww) : 0;
        const unsigned short* arow = xb + (size_t)hwp * C1 + kg * 8;
        const unsigned short* brow = wOB + ((size_t)(p * 8) * 32 + nj * 16 + li) * 32 + kg * 8;
        #pragma unroll
        for (int cc = 0; cc < 8; ++cc) {
            uint4 av = *(const uint4*)(arow + cc * 32);
            if (!valid) av = make_uint4(0, 0, 0, 0);
            uint4 bv = *(const uint4*)(brow + cc * 1024);   // next s: +32*32 u16
            acc = __builtin_amdgcn_mfma_f32_16x16x32_bf16(
                __builtin_bit_cast(bf16x8, av), __builtin_bit_cast(bf16x8, bv), acc, 0, 0, 0);
        }
    }
    // D[row=px = kg*4+r][col=oc = li] (verified mapping, same as k_dmfma)
    int oc = nj * 16 + li;
    if (oc < OFFC) {
        float bs = b_off[oc];
        float4 v;
        v.x = acc[0] + bs; v.y = acc[1] + bs; v.z = acc[2] + bs; v.w = acc[3] + bs;
        int hwd = hw0 + mi * 16 + kg * 4;
        *(float4*)&off[((size_t)b * OFFC + oc) * HWn + hwd] = v;
    }
}

// ---------------- kernel 1c-pre: bilinear metadata table ----------------
__global__ __launch_bounds__(256) void k_meta(const float* __restrict__ off,
                                              int* __restrict__ crdbuf,
                                              float4* __restrict__ w4buf)
{
    int pair = blockIdx.x * 256 + threadIdx.x;   // 0 .. 230399
    int px = pair / 9, p = pair - px * 9;
    int b  = px / HWn, hw = px - b * HWn;
    int h = hw / Wc, w = hw - h * Wc;
    int ii = p / 3, jj = p - ii * 3;

    const float* ob = off + (size_t)b * OFFC * HWn + hw;
    float dy = ob[(2 * p) * HWn];
    float dx = ob[(2 * p + 1) * HWn];
    float mv = ob[(18 + p) * HWn];
    float mask = 1.0f / (1.0f + expf(-mv));
    float ys = dy + (float)(h - 1 + ii);
    float xsv = dx + (float)(w - 1 + jj);
    float y0f = floorf(ys), x0f = floorf(xsv);
    float wy = ys - y0f, wx = xsv - x0f;
    int y0 = (int)y0f, x0 = (int)x0f;
    int y1 = y0 + 1, x1 = x0 + 1;
    float vy0 = (y0 >= 0 && y0 < Hc) ? 1.f : 0.f;
    float vy1 = (y1 >= 0 && y1 < Hc) ? 1.f : 0.f;
    float vx0 = (x0 >= 0 && x0 < Wc) ? 1.f : 0.f;
    float vx1 = (x1 >= 0 && x1 < Wc) ? 1.f : 0.f;
    float4 wv;
    wv.x = mask * (1.f - wy) * (1.f - wx) * vy0 * vx0;
    wv.y = mask * (1.f - wy) * wx         * vy0 * vx1;
    wv.z = mask * wy         * (1.f - wx) * vy1 * vx0;
    wv.w = mask * wy         * wx         * vy1 * vx1;
    int cy0 = min(max(y0, 0), Hc - 1), cy1 = min(max(y1, 0), Hc - 1);
    int cx0 = min(max(x0, 0), Wc - 1), cx1 = min(max(x1, 0), Wc - 1);
    crdbuf[pair] = cy0 | (cy1 << 8) | (cx0 << 16) | (cx1 << 24);
    w4buf[pair]  = wv;
}

// ---------------- kernel 1c: materialize patches v5 (channel-dense reads) -------
__global__ __launch_bounds__(256) void k_gather(const float* __restrict__ xT,
                                                const int* __restrict__ crdbuf,
                                                const float4* __restrict__ w4buf,
                                                unsigned short* __restrict__ Ahi)
{
    int t   = threadIdx.x;
    int wv  = t >> 6, l = t & 63;
    int xcd = blockIdx.x & 7;
    int blk = blockIdx.x >> 3;               // 0..99 within XCD
    int wgl = (xcd * 100 + blk) * 4 + wv;    // global wave 0..3199
    int base = wgl * 72;

    #pragma unroll 2
    for (int i = 0; i < 72; ++i) {
        int pair = base + i;
        int px = pair / 9, p = pair - px * 9;
        int b  = px / HWn;
        int crd = crdbuf[pair];
        float4 w4 = w4buf[pair];
        int cy0 = crd & 255, cy1 = (crd >> 8) & 255;
        int cx0 = (crd >> 16) & 255, cx1 = (crd >> 24) & 255;
        const float* xt = xT + (size_t)b * HWn * C1;
        const float4* g00p = (const float4*)&xt[(size_t)(cy0 * Wc + cx0) * C1];
        const float4* g01p = (const float4*)&xt[(size_t)(cy0 * Wc + cx1) * C1];
        const float4* g10p = (const float4*)&xt[(size_t)(cy1 * Wc + cx0) * C1];
        const float4* g11p = (const float4*)&xt[(size_t)(cy1 * Wc + cx1) * C1];
        float4 g00 = g00p[l], g01 = g01p[l], g10 = g10p[l], g11 = g11p[l];
        float vx = fmaf(w4.x, g00.x, fmaf(w4.y, g01.x, fmaf(w4.z, g10.x, w4.w * g11.x)));
        float vy = fmaf(w4.x, g00.y, fmaf(w4.y, g01.y, fmaf(w4.z, g10.y, w4.w * g11.y)));
        float vz = fmaf(w4.x, g00.z, fmaf(w4.y, g01.z, fmaf(w4.z, g10.z, w4.w * g11.z)));
        float vw = fmaf(w4.x, g00.w, fmaf(w4.y, g01.w, fmaf(w4.z, g10.w, w4.w * g11.w)));
        unsigned h0 = packhi2(vx, vy), h1 = packhi2(vz, vw);
        int s = p * 8 + (l >> 3);
        size_t aidx = ((size_t)s * NPIX + px) * 32 + 4 * (l & 7);
        *(uint2*)&Ahi[aidx] = make_uint2(h0, h1);
    }
}

// ------------- kernel 2: dense streaming MFMA GEMM v8 (A bf16-only) -------------
// (unchanged — vmcnt(1) protocol, see comment)
__global__ __launch_bounds__(256, 4) void k_dmfma(const unsigned short* __restrict__ Ahi,
                                                  const unsigned short* __restrict__ wB1,
                                                  const float* __restrict__ bias,
                                                  float* __restrict__ out)
{
    __shared__ __align__(16) char smem[40960];   // B dbuf [2][256][40] u16
    float* Tb = (float*)smem;                    // epilogue alias [32][33] f32

    int t  = threadIdx.x;
    int wv = t >> 6, lane = t & 63;
    int li = lane & 15, kg = lane >> 4;
    int mi = wv & 1;                   // m-tile (16 px)
    int nh = wv >> 1;                  // oc 128-half

    int mtile = ((blockIdx.x & 7) * 100) + (blockIdx.x >> 3);
    int m0  = mtile * 32;
    int b   = m0 / HWn;
    int hw0 = m0 - b * HWn;
    int row = m0 + mi * 16 + li;

    auto gllB = [&](int s, int buf) {
        const char* src = (const char*)wB1 + (size_t)s * 20480 + wv * 5120 + lane * 16;
        char* dst = smem + buf * 20480 + wv * 5120;
        #pragma unroll
        for (int i = 0; i < 5; ++i)
            __builtin_amdgcn_global_load_lds(
                (const __attribute__((address_space(1))) void*)(src + i * 1024),
                (__attribute__((address_space(3))) void*)(dst + i * 1024),
                16, 0, 0);
    };
    auto loadA = [&](int s, uint4& hh) {
        size_t base = ((size_t)s * NPIX + row) * 32 + kg * 8;
        hh = *(const uint4*)(Ahi + base);
    };

    f32x4 acc[8];
    #pragma unroll
    for (int n = 0; n < 8; ++n) acc[n] = (f32x4){0.f, 0.f, 0.f, 0.f};

    uint4 a0h, a1h, a2h;
    loadA(0, a0h);
    gllB(0, 0);
    loadA(1, a1h);

    auto step = [&](int s, uint4& ch, uint4& lh) {
        if (s == 71) { asm volatile("s_waitcnt vmcnt(0)" ::: "memory"); }
        else         { asm volatile("s_waitcnt vmcnt(1)" ::: "memory"); }
        __builtin_amdgcn_s_barrier();
        __builtin_amdgcn_sched_barrier(0);
        int cur = s & 1;
        if (s < 71) gllB(s + 1, cur ^ 1);
        __builtin_amdgcn_sched_barrier(0);
        if (s < 70) loadA(s + 2, lh);
        __builtin_amdgcn_sched_barrier(0);
        const unsigned short* Bc = (const unsigned short*)(smem + cur * 20480);
        bf16x8 ah = __builtin_bit_cast(bf16x8, ch);
        __builtin_amdgcn_s_setprio(1);
        #pragma unroll
        for (int nt = 0; nt < 8; ++nt) {
            int oc = nh * 128 + nt * 16 + li;
            bf16x8 bv = *(const bf16x8*)&Bc[oc * 40 + kg * 8];
            acc[nt] = __builtin_amdgcn_mfma_f32_16x16x32_bf16(ah, bv, acc[nt], 0, 0, 0);
        }
        __builtin_amdgcn_s_setprio(0);
    };

    for (int s = 0; s < 72; s += 3) {   // 3-slot rotation
        step(s,     a0h, a2h);
        step(s + 1, a1h, a0h);
        step(s + 2, a2h, a1h);
    }

    // ---- epilogue: 8 phases of 32 oc through Tb[32][33] ----
    #pragma unroll
    for (int q = 0; q < 8; ++q) {
        __syncthreads();
        if (nh == (q >> 2)) {
            #pragma unroll
            for (int j = 0; j < 2; ++j) {
                int nt = (q & 3) * 2 + j;
                f32x4 a = acc[nt];
                int rrw = j * 16 + li;              // oc row 0..31
                int col = mi * 16 + kg * 4;         // pixel col
                #pragma unroll
                for (int r = 0; r < 4; ++r)
                    Tb[rrw * 33 + col + r] = a[r];
            }
        }
        __syncthreads();
        int px = t & 31;
        int rw = t >> 5;                    // 0..7
        #pragma unroll
        for (int it = 0; it < 4; ++it) {
            int r  = it * 8 + rw;           // 0..31
            int oc = q * 32 + r;
            out[(size_t)(b * C2 + oc) * HWn + hw0 + px] = Tb[r * 33 + px] + bias[oc];
        }
    }
}

// ---------------- kernel 3: BN stats (per-channel mean, invstd) ----------------
__global__ __launch_bounds__(256) void k_bnstats(const float* __restrict__ out,
                                                 float* __restrict__ stats)
{
    int oc = blockIdx.x;
    double s = 0.0, ss = 0.0;
    for (int i = threadIdx.x; i < NPIX; i += 256) {
        int bb = i / HWn;
        int hw = i - bb * HWn;
        float v = out[(size_t)(bb * C2 + oc) * HWn + hw];
        s  += (double)v;
        ss += (double)v * (double)v;
    }
    __shared__ double ls[256], lss[256];
    ls[threadIdx.x] = s; lss[threadIdx.x] = ss;
    __syncthreads();
    for (int st = 128; st > 0; st >>= 1) {
        if (threadIdx.x < st) {
            ls[threadIdx.x]  += ls[threadIdx.x + st];
            lss[threadIdx.x] += lss[threadIdx.x + st];
        }
        __syncthreads();
    }
    if (threadIdx.x == 0) {
        double mean = ls[0] / (double)NPIX;
        double var  = lss[0] / (double)NPIX - mean * mean;
        stats[oc]       = (float)mean;
        stats[256 + oc] = (float)(1.0 / sqrt(var + 1e-5));
    }
}

// ---------------- kernel 4: BN normalize + affine + SiLU (in-place) ----------------
__global__ __launch_bounds__(256) void k_bnsilu(float* __restrict__ out,
                                                const float* __restrict__ stats,
                                                const float* __restrict__ gamma,
                                                const float* __restrict__ beta)
{
    int n4 = (Bn * C2 * HWn) / 4;
    for (int i = blockIdx.x * blockDim.x + threadIdx.x; i < n4;
         i += gridDim.x * blockDim.x) {
        float4 v = ((float4*)out)[i];
        int e  = i * 4;
        int oc = (e / HWn) & 255;
        float mean = stats[oc];
        float gs   = gamma[oc] * stats[256 + oc];
        float bt   = beta[oc];
        float y;
        y = (v.x - mean) * gs + bt; v.x = y / (1.f + expf(-y));
        y = (v.y - mean) * gs + bt; v.y = y / (1.f + expf(-y));
        y = (v.z - mean) * gs + bt; v.z = y / (1.f + expf(-y));
        y = (v.w - mean) * gs + bt; v.w = y / (1.f + expf(-y));
        ((float4*)out)[i] = v;
    }
}

extern "C" void kernel_launch(void* const* d_in, const int* in_sizes, int n_in,
                              void* d_out, int out_size, void* d_ws, size_t ws_size,
                              hipStream_t stream)
{
    const float* x      = (const float*)d_in[0];
    const float* w_off  = (const float*)d_in[1];
    const float* b_off  = (const float*)d_in[2];
    const float* weight = (const float*)d_in[3];
    const float* bias   = (const float*)d_in[4];
    const float* gamma  = (const float*)d_in[5];
    const float* beta   = (const float*)d_in[6];
    float* out = (float*)d_out;

    // workspace layout (~159 MiB total)
    char* wsb = (char*)d_ws;
    unsigned short* Ahi  = (unsigned short*)(wsb);                 // 117,964,800 B
    float*          xT   = (float*)(wsb + 117964800);              //  26,214,400 B
    unsigned short* xTb  = (unsigned short*)(wsb + 144179200);     //  13,107,200 B
    float*          off  = (float*)(wsb + 157286400);              //   2,764,800 B
    unsigned short* wB1  = (unsigned short*)(wsb + 160051200);     //   1,474,560 B
    unsigned short* wOB  = (unsigned short*)(wsb + 161525760);     //     147,456 B
    int*            crdb = (int*)(wsb + 161673216);                //     921,600 B
    float4*         w4b  = (float4*)(wsb + 162594816);             //   3,686,400 B
    float*         stats = (float*)(wsb + 166281216);              //       2,048 B

    k_wprep    <<<2880, 256, 0, stream>>>(weight, wB1);
    k_wobprep  <<<288, 256, 0, stream>>>(w_off, wOB);
    k_xtrans   <<<6400, 256, 0, stream>>>(x, xT, xTb);
    k_offmfma  <<<800, 256, 0, stream>>>(xTb, wOB, b_off, off);
    k_meta     <<<900, 256, 0, stream>>>(off, crdb, w4b);
    k_gather   <<<800, 256, 0, stream>>>(xT, crdb, w4b, Ahi);
    k_dmfma    <<<800, 256, 0, stream>>>(Ahi, wB1, bias, out);
    k_bnstats  <<<256, 256, 0, stream>>>(out, stats);
    k_bnsilu   <<<2048, 256, 0, stream>>>(out, stats, gamma, beta);
}